// Round 1
// baseline (223.049 us; speedup 1.0000x reference)
//
#include <hip/hip_runtime.h>

#define B_SZ   2
#define NH     16
#define S_LEN  2048
#define DK     64
#define EMB    1024
#define M_TOT  (B_SZ * S_LEN)   // 4096

typedef float          f32x4  __attribute__((ext_vector_type(4)));
typedef unsigned short u16x8  __attribute__((ext_vector_type(8)));
typedef unsigned short u16x4  __attribute__((ext_vector_type(4)));
typedef __bf16         bf16x8 __attribute__((ext_vector_type(8)));

static __device__ __forceinline__ f32x4 mfma16(u16x8 a, u16x8 b, f32x4 c) {
    return __builtin_amdgcn_mfma_f32_16x16x32_bf16(
        __builtin_bit_cast(bf16x8, a), __builtin_bit_cast(bf16x8, b), c, 0, 0, 0);
}

// round-to-nearest-even fp32 -> bf16 (finite inputs)
static __device__ __forceinline__ unsigned short f2bf(float f) {
    unsigned int u = __builtin_bit_cast(unsigned int, f);
    u = (u + 0x7FFFu + ((u >> 16) & 1u)) >> 16;
    return (unsigned short)u;
}

// ---------------------------------------------------------------- convert
__global__ __launch_bounds__(256) void cvt_kernel(
    const float* __restrict__ x,  const float* __restrict__ wq,
    const float* __restrict__ wk, const float* __restrict__ wv,
    unsigned short* __restrict__ xb,  unsigned short* __restrict__ wqb,
    unsigned short* __restrict__ wkb, unsigned short* __restrict__ wvb)
{
    long gid = (long)blockIdx.x * 256 + threadIdx.x;
    long e = gid * 4;
    const float* src; unsigned short* dst; long off;
    if      (e < 4194304L) { src = x;  dst = xb;  off = e; }
    else if (e < 5242880L) { src = wq; dst = wqb; off = e - 4194304L; }
    else if (e < 6291456L) { src = wk; dst = wkb; off = e - 5242880L; }
    else                   { src = wv; dst = wvb; off = e - 6291456L; }
    f32x4 v = *(const f32x4*)(src + off);
    u16x4 u;
    u[0] = f2bf(v[0]); u[1] = f2bf(v[1]); u[2] = f2bf(v[2]); u[3] = f2bf(v[3]);
    *(u16x4*)(dst + off) = u;
}

// ---------------------------------------------------------------- QKV GEMM
// C[m,n] = sum_k xb[m,k] * W[n,k] + bias[n]; write bf16 to [B,H,S,D]
#define BM 128
#define BN 128
#define BK 64
#define LDK 72   // padded LDS stride (bf16 elems)

__global__ __launch_bounds__(256) void qkv_gemm(
    const unsigned short* __restrict__ xb,
    const unsigned short* __restrict__ wb,   // 3 x [1024][1024] bf16
    const float* __restrict__ bq, const float* __restrict__ bk,
    const float* __restrict__ bv,
    unsigned short* __restrict__ qkv)        // 3 x [B,H,S,D] bf16
{
    const int tid  = threadIdx.x;
    const int lane = tid & 63;
    const int wid  = tid >> 6;
    const int wm   = wid >> 1, wn = wid & 1;
    const int n0   = blockIdx.x * BN;
    const int m0   = blockIdx.y * BM;
    const int mat  = blockIdx.z;

    const unsigned short* wmat = wb + (size_t)mat * (1024 * 1024);
    const float* bias = (mat == 0) ? bq : ((mat == 1) ? bk : bv);
    unsigned short* dst = qkv + (size_t)mat * ((size_t)M_TOT * EMB);

    __shared__ __align__(16) unsigned short Al[BM * LDK];
    __shared__ __align__(16) unsigned short Bl[BN * LDK];

    f32x4 acc[4][4];
#pragma unroll
    for (int i = 0; i < 4; ++i)
#pragma unroll
        for (int j = 0; j < 4; ++j)
            acc[i][j] = (f32x4){0.f, 0.f, 0.f, 0.f};

    for (int k0 = 0; k0 < EMB; k0 += BK) {
        // stage A (128x64) and B (128x64) as bf16, padded stride
#pragma unroll
        for (int i = 0; i < 4; ++i) {
            int cc  = tid + i * 256;            // 0..1023
            int row = cc >> 3, c8 = cc & 7;
            u16x8 va = *(const u16x8*)(xb   + (size_t)(m0 + row) * EMB + k0 + c8 * 8);
            *(u16x8*)&Al[row * LDK + c8 * 8] = va;
            u16x8 vb = *(const u16x8*)(wmat + (size_t)(n0 + row) * EMB + k0 + c8 * 8);
            *(u16x8*)&Bl[row * LDK + c8 * 8] = vb;
        }
        __syncthreads();

        const int ko = (lane >> 4) * 8;
#pragma unroll
        for (int kk = 0; kk < 2; ++kk) {
            u16x8 a[4], b[4];
#pragma unroll
            for (int i = 0; i < 4; ++i)
                a[i] = *(const u16x8*)&Al[(wm * 64 + i * 16 + (lane & 15)) * LDK + kk * 32 + ko];
#pragma unroll
            for (int j = 0; j < 4; ++j)
                b[j] = *(const u16x8*)&Bl[(wn * 64 + j * 16 + (lane & 15)) * LDK + kk * 32 + ko];
#pragma unroll
            for (int i = 0; i < 4; ++i)
#pragma unroll
                for (int j = 0; j < 4; ++j)
                    acc[i][j] = mfma16(a[i], b[j], acc[i][j]);
        }
        __syncthreads();
    }

    // epilogue: + bias, store bf16 at [b][h][s][d]
#pragma unroll
    for (int j = 0; j < 4; ++j) {
        int n = n0 + wn * 64 + j * 16 + (lane & 15);
        float bvv = bias[n];
        int h = n >> 6, d = n & 63;
#pragma unroll
        for (int i = 0; i < 4; ++i) {
#pragma unroll
            for (int r = 0; r < 4; ++r) {
                int m = m0 + wm * 64 + i * 16 + ((lane >> 4) << 2) + r;
                int bb = m >> 11, s = m & 2047;
                dst[((size_t)((bb * NH + h) * S_LEN + s)) * DK + d] =
                    f2bf(acc[i][j][r] + bvv);
            }
        }
    }
}

// ---------------------------------------------------------------- attention
#define QT 64
#define KT 64
#define LDA 72

__global__ __launch_bounds__(256) void attn_kernel(
    const unsigned short* __restrict__ Q,
    const unsigned short* __restrict__ K,
    const unsigned short* __restrict__ V,
    const int* __restrict__ mskp,
    float* __restrict__ out)
{
    const int tid = threadIdx.x, lane = tid & 63, wid = tid >> 6;
    const int tq = blockIdx.x;           // 0..31
    const int h  = blockIdx.y, b = blockIdx.z;
    const int q0 = tq * QT;
    const size_t hoff = ((size_t)(b * NH + h)) * S_LEN * DK;
    const unsigned short* Qh = Q + hoff;
    const unsigned short* Kh = K + hoff;
    const unsigned short* Vh = V + hoff;
    const int msk = *mskp;
    const int ntiles = msk ? (tq + 1) : (S_LEN / KT);

    __shared__ __align__(16) unsigned short Kl[KT * LDA];
    __shared__ __align__(16) unsigned short Vt[DK * LDA];
    __shared__ __align__(16) unsigned short Pl[4 * 16 * LDA];

    const int ko = (lane >> 4) * 8;
    const int qlr = ((lane >> 4) << 2);        // local row base for acc regs

    // Q fragments, held for the whole block
    u16x8 qf[2];
    {
        int qrow = q0 + wid * 16 + (lane & 15);
        qf[0] = *(const u16x8*)(Qh + (size_t)qrow * DK + ko);
        qf[1] = *(const u16x8*)(Qh + (size_t)qrow * DK + 32 + ko);
    }

    f32x4 o[4];
#pragma unroll
    for (int d = 0; d < 4; ++d) o[d] = (f32x4){0.f, 0.f, 0.f, 0.f};
    float m[4], l[4];
#pragma unroll
    for (int r = 0; r < 4; ++r) { m[r] = -1e30f; l[r] = 0.f; }

    const int pbase = wid * 16 * LDA;

    for (int t = 0; t < ntiles; ++t) {
        const int kv0 = t * KT;
        __syncthreads();
        // stage K row-major, V transposed
#pragma unroll
        for (int i = 0; i < 2; ++i) {
            int cc = tid + i * 256;             // 0..511
            int row = cc >> 3, c8 = cc & 7;
            u16x8 kvv = *(const u16x8*)(Kh + (size_t)(kv0 + row) * DK + c8 * 8);
            *(u16x8*)&Kl[row * LDA + c8 * 8] = kvv;
            u16x8 vvv = *(const u16x8*)(Vh + (size_t)(kv0 + row) * DK + c8 * 8);
#pragma unroll
            for (int e = 0; e < 8; ++e)
                Vt[(c8 * 8 + e) * LDA + row] = vvv[e];
        }
        __syncthreads();

        // S = Q K^T  (4 col-subtiles of 16)
        f32x4 sf[4];
#pragma unroll
        for (int f = 0; f < 4; ++f) {
            u16x8 k0f = *(const u16x8*)&Kl[(f * 16 + (lane & 15)) * LDA + ko];
            u16x8 k1f = *(const u16x8*)&Kl[(f * 16 + (lane & 15)) * LDA + 32 + ko];
            f32x4 sv = (f32x4){0.f, 0.f, 0.f, 0.f};
            sv = mfma16(qf[0], k0f, sv);
            sv = mfma16(qf[1], k1f, sv);
            sf[f] = sv;
        }

        // scale + causal mask
        float p_[4][4];
#pragma unroll
        for (int f = 0; f < 4; ++f) {
#pragma unroll
            for (int r = 0; r < 4; ++r) {
                int col = kv0 + f * 16 + (lane & 15);
                int row = q0 + wid * 16 + qlr + r;
                float sv = sf[f][r] * 0.125f;
                if (msk && (col > row)) sv = -1e30f;
                p_[f][r] = sv;
            }
        }

        // online softmax (rows live across 16 lanes sharing lane>>4)
        float alpha[4];
#pragma unroll
        for (int r = 0; r < 4; ++r) {
            float mt = fmaxf(fmaxf(p_[0][r], p_[1][r]), fmaxf(p_[2][r], p_[3][r]));
#pragma unroll
            for (int off = 1; off < 16; off <<= 1)
                mt = fmaxf(mt, __shfl_xor(mt, off, 64));
            float mn = fmaxf(m[r], mt);
            float al = __expf(m[r] - mn);
            float ls = 0.f;
#pragma unroll
            for (int f = 0; f < 4; ++f) {
                float p = __expf(p_[f][r] - mn);
                p_[f][r] = p;
                ls += p;
            }
#pragma unroll
            for (int off = 1; off < 16; off <<= 1)
                ls += __shfl_xor(ls, off, 64);
            m[r] = mn;
            l[r] = l[r] * al + ls;
            alpha[r] = al;
        }
#pragma unroll
        for (int d = 0; d < 4; ++d)
#pragma unroll
            for (int r = 0; r < 4; ++r)
                o[d][r] *= alpha[r];

        // P -> LDS (bf16), per-wave private region
#pragma unroll
        for (int f = 0; f < 4; ++f)
#pragma unroll
            for (int r = 0; r < 4; ++r)
                Pl[pbase + (qlr + r) * LDA + f * 16 + (lane & 15)] = f2bf(p_[f][r]);
        asm volatile("s_waitcnt lgkmcnt(0)" ::: "memory");

        // O += P V
        u16x8 pa0 = *(const u16x8*)&Pl[pbase + (lane & 15) * LDA + ko];
        u16x8 pa1 = *(const u16x8*)&Pl[pbase + (lane & 15) * LDA + 32 + ko];
#pragma unroll
        for (int d = 0; d < 4; ++d) {
            u16x8 v0 = *(const u16x8*)&Vt[(d * 16 + (lane & 15)) * LDA + ko];
            u16x8 v1 = *(const u16x8*)&Vt[(d * 16 + (lane & 15)) * LDA + 32 + ko];
            o[d] = mfma16(pa0, v0, o[d]);
            o[d] = mfma16(pa1, v1, o[d]);
        }
    }

    // epilogue: normalize, write fp32 [B,S,E]
#pragma unroll
    for (int r = 0; r < 4; ++r) {
        float inv = 1.f / l[r];
        int row = q0 + wid * 16 + qlr + r;
        float* orow = out + ((size_t)(b * S_LEN + row)) * EMB + h * DK;
#pragma unroll
        for (int d = 0; d < 4; ++d)
            orow[d * 16 + (lane & 15)] = o[d][r] * inv;
    }
}

// ---------------------------------------------------------------- launch
extern "C" void kernel_launch(void* const* d_in, const int* in_sizes, int n_in,
                              void* d_out, int out_size, void* d_ws, size_t ws_size,
                              hipStream_t stream)
{
    const float* x  = (const float*)d_in[0];
    const float* wq = (const float*)d_in[1];
    const float* bq = (const float*)d_in[2];
    const float* wk = (const float*)d_in[3];
    const float* bk = (const float*)d_in[4];
    const float* wv = (const float*)d_in[5];
    const float* bv = (const float*)d_in[6];
    const int* msk  = (const int*)d_in[7];
    float* out = (float*)d_out;

    unsigned short* xb  = (unsigned short*)d_ws;              // 4096*1024
    unsigned short* wb  = xb + (size_t)M_TOT * EMB;           // 3*1024*1024
    unsigned short* qkv = wb + (size_t)3 * 1024 * 1024;       // 3*4194304

    cvt_kernel<<<7168, 256, 0, stream>>>(x, wq, wk, wv,
                                         xb, wb, wb + 1024 * 1024, wb + 2 * 1024 * 1024);
    qkv_gemm<<<dim3(8, 32, 3), 256, 0, stream>>>(xb, wb, bq, bk, bv, qkv);
    attn_kernel<<<dim3(32, 16, 2), 256, 0, stream>>>(
        qkv, qkv + (size_t)M_TOT * EMB, qkv + (size_t)2 * M_TOT * EMB, msk, out);
}

// Round 2
// 144.156 us; speedup vs baseline: 1.5473x; 1.5473x over previous
//
#include <hip/hip_runtime.h>

#define B_SZ   2
#define NH     16
#define S_LEN  2048
#define DK     64
#define EMB    1024
#define M_TOT  (B_SZ * S_LEN)   // 4096

typedef float          f32x4  __attribute__((ext_vector_type(4)));
typedef unsigned short u16x8  __attribute__((ext_vector_type(8)));
typedef unsigned short u16x4  __attribute__((ext_vector_type(4)));
typedef __bf16         bf16x8 __attribute__((ext_vector_type(8)));

static __device__ __forceinline__ f32x4 mfma16(u16x8 a, u16x8 b, f32x4 c) {
    return __builtin_amdgcn_mfma_f32_16x16x32_bf16(
        __builtin_bit_cast(bf16x8, a), __builtin_bit_cast(bf16x8, b), c, 0, 0, 0);
}

// round-to-nearest-even fp32 -> bf16 (finite inputs)
static __device__ __forceinline__ unsigned short f2bf(float f) {
    unsigned int u = __builtin_bit_cast(unsigned int, f);
    u = (u + 0x7FFFu + ((u >> 16) & 1u)) >> 16;
    return (unsigned short)u;
}

// ---------------------------------------------------------------- convert
__global__ __launch_bounds__(256) void cvt_kernel(
    const float* __restrict__ x,  const float* __restrict__ wq,
    const float* __restrict__ wk, const float* __restrict__ wv,
    unsigned short* __restrict__ xb,  unsigned short* __restrict__ wqb,
    unsigned short* __restrict__ wkb, unsigned short* __restrict__ wvb)
{
    long gid = (long)blockIdx.x * 256 + threadIdx.x;
    long e = gid * 4;
    const float* src; unsigned short* dst; long off;
    if      (e < 4194304L) { src = x;  dst = xb;  off = e; }
    else if (e < 5242880L) { src = wq; dst = wqb; off = e - 4194304L; }
    else if (e < 6291456L) { src = wk; dst = wkb; off = e - 5242880L; }
    else                   { src = wv; dst = wvb; off = e - 6291456L; }
    f32x4 v = *(const f32x4*)(src + off);
    u16x4 u;
    u[0] = f2bf(v[0]); u[1] = f2bf(v[1]); u[2] = f2bf(v[2]); u[3] = f2bf(v[3]);
    *(u16x4*)(dst + off) = u;
}

// ---------------------------------------------------------------- QKV GEMM
// C[m,n] = sum_k xb[m,k] * W[n,k] + bias[n]; write bf16 to [B,H,S,D]
#define BM 128
#define BN 128
#define BK 64
#define LDK 72   // padded LDS stride (bf16 elems)

__global__ __launch_bounds__(256) void qkv_gemm(
    const unsigned short* __restrict__ xb,
    const unsigned short* __restrict__ wb,   // 3 x [1024][1024] bf16
    const float* __restrict__ bq, const float* __restrict__ bk,
    const float* __restrict__ bv,
    unsigned short* __restrict__ qkv)        // 3 x [B,H,S,D] bf16
{
    const int tid  = threadIdx.x;
    const int lane = tid & 63;
    const int wid  = tid >> 6;
    const int wm   = wid >> 1, wn = wid & 1;
    const int n0   = blockIdx.x * BN;
    const int m0   = blockIdx.y * BM;
    const int mat  = blockIdx.z;

    const unsigned short* wmat = wb + (size_t)mat * (1024 * 1024);
    const float* bias = (mat == 0) ? bq : ((mat == 1) ? bk : bv);
    unsigned short* dst = qkv + (size_t)mat * ((size_t)M_TOT * EMB);

    __shared__ __align__(16) unsigned short Al[BM * LDK];
    __shared__ __align__(16) unsigned short Bl[BN * LDK];

    f32x4 acc[4][4];
#pragma unroll
    for (int i = 0; i < 4; ++i)
#pragma unroll
        for (int j = 0; j < 4; ++j)
            acc[i][j] = (f32x4){0.f, 0.f, 0.f, 0.f};

    for (int k0 = 0; k0 < EMB; k0 += BK) {
        // stage A (128x64) and B (128x64) as bf16, padded stride
#pragma unroll
        for (int i = 0; i < 4; ++i) {
            int cc  = tid + i * 256;            // 0..1023
            int row = cc >> 3, c8 = cc & 7;
            u16x8 va = *(const u16x8*)(xb   + (size_t)(m0 + row) * EMB + k0 + c8 * 8);
            *(u16x8*)&Al[row * LDK + c8 * 8] = va;
            u16x8 vb = *(const u16x8*)(wmat + (size_t)(n0 + row) * EMB + k0 + c8 * 8);
            *(u16x8*)&Bl[row * LDK + c8 * 8] = vb;
        }
        __syncthreads();

        const int ko = (lane >> 4) * 8;
#pragma unroll
        for (int kk = 0; kk < 2; ++kk) {
            u16x8 a[4], b[4];
#pragma unroll
            for (int i = 0; i < 4; ++i)
                a[i] = *(const u16x8*)&Al[(wm * 64 + i * 16 + (lane & 15)) * LDK + kk * 32 + ko];
#pragma unroll
            for (int j = 0; j < 4; ++j)
                b[j] = *(const u16x8*)&Bl[(wn * 64 + j * 16 + (lane & 15)) * LDK + kk * 32 + ko];
#pragma unroll
            for (int i = 0; i < 4; ++i)
#pragma unroll
                for (int j = 0; j < 4; ++j)
                    acc[i][j] = mfma16(a[i], b[j], acc[i][j]);
        }
        __syncthreads();
    }

    // epilogue: + bias, store bf16 at [b][h][s][d]
#pragma unroll
    for (int j = 0; j < 4; ++j) {
        int n = n0 + wn * 64 + j * 16 + (lane & 15);
        float bvv = bias[n];
        int h = n >> 6, d = n & 63;
#pragma unroll
        for (int i = 0; i < 4; ++i) {
#pragma unroll
            for (int r = 0; r < 4; ++r) {
                int m = m0 + wm * 64 + i * 16 + ((lane >> 4) << 2) + r;
                int bb = m >> 11, s = m & 2047;
                dst[((size_t)((bb * NH + h) * S_LEN + s)) * DK + d] =
                    f2bf(acc[i][j][r] + bvv);
            }
        }
    }
}

// ---------------------------------------------------------------- attention
#define QT 64
#define KT 64
#define LDA 72

__global__ __launch_bounds__(256) void attn_kernel(
    const unsigned short* __restrict__ Q,
    const unsigned short* __restrict__ K,
    const unsigned short* __restrict__ V,
    const int* __restrict__ mskp,
    float* __restrict__ out)
{
    const int tid = threadIdx.x, lane = tid & 63, wid = tid >> 6;
    // grid: x = (b,h) combo (32), y = q-tile (32).  Swapped so that blocks
    // co-resident on a CU (linear ids differing by 256) get DIFFERENT tq
    // -> balanced causal work per CU.
    const int bh = blockIdx.x;
    const int h  = bh & 15, b = bh >> 4;
    const int tq = blockIdx.y;
    const int q0 = tq * QT;
    const size_t hoff = ((size_t)(b * NH + h)) * S_LEN * DK;
    const unsigned short* Qh = Q + hoff;
    const unsigned short* Kh = K + hoff;
    const unsigned short* Vh = V + hoff;
    const int msk = *mskp;
    const int ntiles = msk ? (tq + 1) : (S_LEN / KT);

    __shared__ __align__(16) unsigned short Kl[KT * LDA];
    __shared__ __align__(16) unsigned short Vt[DK * LDA];
    __shared__ __align__(16) unsigned short Pl[4 * 16 * LDA];

    const int ko  = (lane >> 4) * 8;
    const int l15 = lane & 15;
    const int qlr = ((lane >> 4) << 2);        // local row base for acc regs

    // Q fragments, held for the whole block
    u16x8 qf[2];
    {
        int qrow = q0 + wid * 16 + l15;
        qf[0] = *(const u16x8*)(Qh + (size_t)qrow * DK + ko);
        qf[1] = *(const u16x8*)(Qh + (size_t)qrow * DK + 32 + ko);
    }

    f32x4 o[4];
#pragma unroll
    for (int d = 0; d < 4; ++d) o[d] = (f32x4){0.f, 0.f, 0.f, 0.f};
    float m[4], l[4];
#pragma unroll
    for (int r = 0; r < 4; ++r) { m[r] = -1e30f; l[r] = 0.f; }

    const int pbase = wid * 16 * LDA;
    const int srow0 = tid >> 3, sc8 = tid & 7;          // staging coords, i=0
    const int srow1 = (tid + 256) >> 3;                 // i=1 (same c8)

    // prefetch registers (T14 async-STAGE split)
    u16x8 kr[2], vr[2];
    {
        kr[0] = *(const u16x8*)(Kh + (size_t)srow0 * DK + sc8 * 8);
        vr[0] = *(const u16x8*)(Vh + (size_t)srow0 * DK + sc8 * 8);
        kr[1] = *(const u16x8*)(Kh + (size_t)srow1 * DK + sc8 * 8);
        vr[1] = *(const u16x8*)(Vh + (size_t)srow1 * DK + sc8 * 8);
    }

    for (int t = 0; t < ntiles; ++t) {
        __syncthreads();   // all waves done reading previous LDS tile
        // LDS write from prefetch regs.  K: vector row-major (even bank
        // spread).  V: transposed scalar with key-axis XOR swizzle by
        // (d>>3)<<3 -> banks 4e + 4(w^c8) + r/2, 2-way max (free).
        {
            *(u16x8*)&Kl[srow0 * LDA + sc8 * 8] = kr[0];
            *(u16x8*)&Kl[srow1 * LDA + sc8 * 8] = kr[1];
#pragma unroll
            for (int e = 0; e < 8; ++e) {
                Vt[(sc8 * 8 + e) * LDA + (srow0 ^ (sc8 << 3))] = vr[0][e];
                Vt[(sc8 * 8 + e) * LDA + (srow1 ^ (sc8 << 3))] = vr[1][e];
            }
        }
        __syncthreads();

        // prefetch next tile into regs; latency hides under compute below
        if (t + 1 < ntiles) {
            const unsigned short* Kn = Kh + (size_t)(t + 1) * KT * DK;
            const unsigned short* Vn = Vh + (size_t)(t + 1) * KT * DK;
            kr[0] = *(const u16x8*)(Kn + (size_t)srow0 * DK + sc8 * 8);
            vr[0] = *(const u16x8*)(Vn + (size_t)srow0 * DK + sc8 * 8);
            kr[1] = *(const u16x8*)(Kn + (size_t)srow1 * DK + sc8 * 8);
            vr[1] = *(const u16x8*)(Vn + (size_t)srow1 * DK + sc8 * 8);
        }

        // S = Q K^T  (4 col-subtiles of 16)
        f32x4 sf[4];
        __builtin_amdgcn_s_setprio(1);
#pragma unroll
        for (int f = 0; f < 4; ++f) {
            u16x8 k0f = *(const u16x8*)&Kl[(f * 16 + l15) * LDA + ko];
            u16x8 k1f = *(const u16x8*)&Kl[(f * 16 + l15) * LDA + 32 + ko];
            f32x4 sv = (f32x4){0.f, 0.f, 0.f, 0.f};
            sv = mfma16(qf[0], k0f, sv);
            sv = mfma16(qf[1], k1f, sv);
            sf[f] = sv;
        }
        __builtin_amdgcn_s_setprio(0);

        // scale + causal mask (mask only on the diagonal tile)
        const bool diag = msk && (t == ntiles - 1);
        float p_[4][4];
#pragma unroll
        for (int f = 0; f < 4; ++f) {
#pragma unroll
            for (int r = 0; r < 4; ++r) {
                float sv = sf[f][r] * 0.125f;
                if (diag && (f * 16 + l15 > wid * 16 + qlr + r)) sv = -1e30f;
                p_[f][r] = sv;
            }
        }

        // online softmax (rows live across 16 lanes sharing lane>>4)
        float alpha[4];
#pragma unroll
        for (int r = 0; r < 4; ++r) {
            float mt = fmaxf(fmaxf(p_[0][r], p_[1][r]), fmaxf(p_[2][r], p_[3][r]));
#pragma unroll
            for (int off = 1; off < 16; off <<= 1)
                mt = fmaxf(mt, __shfl_xor(mt, off, 64));
            float mn = fmaxf(m[r], mt);
            float al = __expf(m[r] - mn);
            float ls = 0.f;
#pragma unroll
            for (int f = 0; f < 4; ++f) {
                float p = __expf(p_[f][r] - mn);
                p_[f][r] = p;
                ls += p;
            }
#pragma unroll
            for (int off = 1; off < 16; off <<= 1)
                ls += __shfl_xor(ls, off, 64);
            m[r] = mn;
            l[r] = l[r] * al + ls;
            alpha[r] = al;
        }
#pragma unroll
        for (int d = 0; d < 4; ++d)
#pragma unroll
            for (int r = 0; r < 4; ++r)
                o[d][r] *= alpha[r];

        // P -> LDS (bf16), per-wave private region
#pragma unroll
        for (int f = 0; f < 4; ++f)
#pragma unroll
            for (int r = 0; r < 4; ++r)
                Pl[pbase + (qlr + r) * LDA + f * 16 + l15] = f2bf(p_[f][r]);

        // O += P V
        u16x8 pa0 = *(const u16x8*)&Pl[pbase + l15 * LDA + ko];
        u16x8 pa1 = *(const u16x8*)&Pl[pbase + l15 * LDA + 32 + ko];
        __builtin_amdgcn_s_setprio(1);
#pragma unroll
        for (int d = 0; d < 4; ++d) {
            int vd = d * 16 + l15;
            int sw = ((vd >> 3) & 7) << 3;
            u16x8 v0 = *(const u16x8*)&Vt[vd * LDA + (ko ^ sw)];
            u16x8 v1 = *(const u16x8*)&Vt[vd * LDA + ((ko + 32) ^ sw)];
            o[d] = mfma16(pa0, v0, o[d]);
            o[d] = mfma16(pa1, v1, o[d]);
        }
        __builtin_amdgcn_s_setprio(0);
    }

    // epilogue: normalize, write fp32 [B,S,E]
#pragma unroll
    for (int r = 0; r < 4; ++r) {
        float inv = 1.f / l[r];
        int row = q0 + wid * 16 + qlr + r;
        float* orow = out + ((size_t)(b * S_LEN + row)) * EMB + h * DK;
#pragma unroll
        for (int d = 0; d < 4; ++d)
            orow[d * 16 + l15] = o[d][r] * inv;
    }
}

// ---------------------------------------------------------------- launch
extern "C" void kernel_launch(void* const* d_in, const int* in_sizes, int n_in,
                              void* d_out, int out_size, void* d_ws, size_t ws_size,
                              hipStream_t stream)
{
    const float* x  = (const float*)d_in[0];
    const float* wq = (const float*)d_in[1];
    const float* bq = (const float*)d_in[2];
    const float* wk = (const float*)d_in[3];
    const float* bk = (const float*)d_in[4];
    const float* wv = (const float*)d_in[5];
    const float* bv = (const float*)d_in[6];
    const int* msk  = (const int*)d_in[7];
    float* out = (float*)d_out;

    unsigned short* xb  = (unsigned short*)d_ws;              // 4096*1024
    unsigned short* wb  = xb + (size_t)M_TOT * EMB;           // 3*1024*1024
    unsigned short* qkv = wb + (size_t)3 * 1024 * 1024;       // 3*4194304

    cvt_kernel<<<7168, 256, 0, stream>>>(x, wq, wk, wv,
                                         xb, wb, wb + 1024 * 1024, wb + 2 * 1024 * 1024);
    qkv_gemm<<<dim3(8, 32, 3), 256, 0, stream>>>(xb, wb, bq, bk, bv, qkv);
    attn_kernel<<<dim3(32, 32, 1), 256, 0, stream>>>(
        qkv, qkv + (size_t)M_TOT * EMB, qkv + (size_t)2 * M_TOT * EMB, msk, out);
}

// Round 3
// 137.223 us; speedup vs baseline: 1.6255x; 1.0505x over previous
//
#include <hip/hip_runtime.h>

#define B_SZ   2
#define NH     16
#define S_LEN  2048
#define DK     64
#define EMB    1024
#define M_TOT  (B_SZ * S_LEN)   // 4096

typedef float          f32x4  __attribute__((ext_vector_type(4)));
typedef unsigned short u16x8  __attribute__((ext_vector_type(8)));
typedef unsigned short u16x4  __attribute__((ext_vector_type(4)));
typedef __bf16         bf16x8 __attribute__((ext_vector_type(8)));

static __device__ __forceinline__ f32x4 mfma16(u16x8 a, u16x8 b, f32x4 c) {
    return __builtin_amdgcn_mfma_f32_16x16x32_bf16(
        __builtin_bit_cast(bf16x8, a), __builtin_bit_cast(bf16x8, b), c, 0, 0, 0);
}

// round-to-nearest-even fp32 -> bf16 (finite inputs)
static __device__ __forceinline__ unsigned short f2bf(float f) {
    unsigned int u = __builtin_bit_cast(unsigned int, f);
    u = (u + 0x7FFFu + ((u >> 16) & 1u)) >> 16;
    return (unsigned short)u;
}

// ---------------------------------------------------------------- convert
__global__ __launch_bounds__(256) void cvt_kernel(
    const float* __restrict__ x,  const float* __restrict__ wq,
    const float* __restrict__ wk, const float* __restrict__ wv,
    unsigned short* __restrict__ xb,  unsigned short* __restrict__ wqb,
    unsigned short* __restrict__ wkb, unsigned short* __restrict__ wvb)
{
    long gid = (long)blockIdx.x * 256 + threadIdx.x;
    long e = gid * 4;
    const float* src; unsigned short* dst; long off;
    if      (e < 4194304L) { src = x;  dst = xb;  off = e; }
    else if (e < 5242880L) { src = wq; dst = wqb; off = e - 4194304L; }
    else if (e < 6291456L) { src = wk; dst = wkb; off = e - 5242880L; }
    else                   { src = wv; dst = wvb; off = e - 6291456L; }
    f32x4 v = *(const f32x4*)(src + off);
    u16x4 u;
    u[0] = f2bf(v[0]); u[1] = f2bf(v[1]); u[2] = f2bf(v[2]); u[3] = f2bf(v[3]);
    *(u16x4*)(dst + off) = u;
}

// ---------------------------------------------------------------- QKV GEMM
// C[m,n] = sum_k xb[m,k] * W[n,k] + bias[n]; write bf16 to [B,H,S,D]
#define BM 128
#define BN 128
#define BK 64
#define LDK 72   // padded LDS stride (bf16 elems)

__global__ __launch_bounds__(256) void qkv_gemm(
    const unsigned short* __restrict__ xb,
    const unsigned short* __restrict__ wb,   // 3 x [1024][1024] bf16
    const float* __restrict__ bq, const float* __restrict__ bk,
    const float* __restrict__ bv,
    unsigned short* __restrict__ qkv)        // 3 x [B,H,S,D] bf16
{
    const int tid  = threadIdx.x;
    const int lane = tid & 63;
    const int wid  = tid >> 6;
    const int wm   = wid >> 1, wn = wid & 1;
    const int n0   = blockIdx.x * BN;
    const int m0   = blockIdx.y * BM;
    const int mat  = blockIdx.z;

    const unsigned short* wmat = wb + (size_t)mat * (1024 * 1024);
    const float* bias = (mat == 0) ? bq : ((mat == 1) ? bk : bv);
    unsigned short* dst = qkv + (size_t)mat * ((size_t)M_TOT * EMB);

    __shared__ __align__(16) unsigned short Al[BM * LDK];
    __shared__ __align__(16) unsigned short Bl[BN * LDK];

    f32x4 acc[4][4];
#pragma unroll
    for (int i = 0; i < 4; ++i)
#pragma unroll
        for (int j = 0; j < 4; ++j)
            acc[i][j] = (f32x4){0.f, 0.f, 0.f, 0.f};

    for (int k0 = 0; k0 < EMB; k0 += BK) {
        // stage A (128x64) and B (128x64) as bf16, padded stride
#pragma unroll
        for (int i = 0; i < 4; ++i) {
            int cc  = tid + i * 256;            // 0..1023
            int row = cc >> 3, c8 = cc & 7;
            u16x8 va = *(const u16x8*)(xb   + (size_t)(m0 + row) * EMB + k0 + c8 * 8);
            *(u16x8*)&Al[row * LDK + c8 * 8] = va;
            u16x8 vb = *(const u16x8*)(wmat + (size_t)(n0 + row) * EMB + k0 + c8 * 8);
            *(u16x8*)&Bl[row * LDK + c8 * 8] = vb;
        }
        __syncthreads();

        const int ko = (lane >> 4) * 8;
#pragma unroll
        for (int kk = 0; kk < 2; ++kk) {
            u16x8 a[4], b[4];
#pragma unroll
            for (int i = 0; i < 4; ++i)
                a[i] = *(const u16x8*)&Al[(wm * 64 + i * 16 + (lane & 15)) * LDK + kk * 32 + ko];
#pragma unroll
            for (int j = 0; j < 4; ++j)
                b[j] = *(const u16x8*)&Bl[(wn * 64 + j * 16 + (lane & 15)) * LDK + kk * 32 + ko];
#pragma unroll
            for (int i = 0; i < 4; ++i)
#pragma unroll
                for (int j = 0; j < 4; ++j)
                    acc[i][j] = mfma16(a[i], b[j], acc[i][j]);
        }
        __syncthreads();
    }

    // epilogue: + bias, store bf16 at [b][h][s][d]
#pragma unroll
    for (int j = 0; j < 4; ++j) {
        int n = n0 + wn * 64 + j * 16 + (lane & 15);
        float bvv = bias[n];
        int h = n >> 6, d = n & 63;
#pragma unroll
        for (int i = 0; i < 4; ++i) {
#pragma unroll
            for (int r = 0; r < 4; ++r) {
                int m = m0 + wm * 64 + i * 16 + ((lane >> 4) << 2) + r;
                int bb = m >> 11, s = m & 2047;
                dst[((size_t)((bb * NH + h) * S_LEN + s)) * DK + d] =
                    f2bf(acc[i][j][r] + bvv);
            }
        }
    }
}

// ---------------------------------------------------------------- attention
// 8 waves: waves 0-3 (group 0) process even K-tiles, waves 4-7 (group 1)
// process odd K-tiles.  Each group keeps its own online-softmax state and
// its own K/V LDS buffers; states merge once at the end via LDS.
// Halves the serial per-block dependence chain and doubles waves/block.
#define QT 64
#define KT 64
#define LDA 72

__global__ __launch_bounds__(512) void attn_kernel(
    const unsigned short* __restrict__ Q,
    const unsigned short* __restrict__ K,
    const unsigned short* __restrict__ V,
    const int* __restrict__ mskp,
    float* __restrict__ out)
{
    const int tid = threadIdx.x, lane = tid & 63, wid = tid >> 6;
    const int grp = wid >> 2;            // K-tile parity group
    const int qw  = wid & 3;             // q sub-tile (16 rows)
    const int bh = blockIdx.x;
    const int h  = bh & 15, b = bh >> 4;
    const int tq = blockIdx.y;
    const int q0 = tq * QT;
    const size_t hoff = ((size_t)(b * NH + h)) * S_LEN * DK;
    const unsigned short* Qh = Q + hoff;
    const unsigned short* Kh = K + hoff;
    const unsigned short* Vh = V + hoff;
    const int msk = *mskp;
    const int ntiles = msk ? (tq + 1) : (S_LEN / KT);
    const int npairs = (ntiles + 1) >> 1;

    __shared__ __align__(16) unsigned short Kl[2][KT * LDA];
    __shared__ __align__(16) unsigned short Vt[2][DK * LDA];
    __shared__ __align__(16) unsigned short Pl[8 * 16 * LDA];  // P + merge buf

    const int ko  = (lane >> 4) * 8;
    const int l15 = lane & 15;
    const int qlr = ((lane >> 4) << 2);

    // Q fragments (groups load the same rows — 8KB redundant fetch, cheap)
    u16x8 qf[2];
    {
        int qrow = q0 + qw * 16 + l15;
        qf[0] = *(const u16x8*)(Qh + (size_t)qrow * DK + ko);
        qf[1] = *(const u16x8*)(Qh + (size_t)qrow * DK + 32 + ko);
    }

    f32x4 o[4];
#pragma unroll
    for (int d = 0; d < 4; ++d) o[d] = (f32x4){0.f, 0.f, 0.f, 0.f};
    float m[4], l[4];
#pragma unroll
    for (int r = 0; r < 4; ++r) { m[r] = -1e30f; l[r] = 0.f; }

    const int pbase = wid * 16 * LDA;
    const int gtid  = tid & 255;               // tid within group
    const int srow0 = gtid >> 3, sc8 = gtid & 7;
    const int srow1 = srow0 + 32;

    unsigned short* Kg = Kl[grp];
    unsigned short* Vg = Vt[grp];

    // prefetch this group's first tile
    u16x8 kr[2], vr[2];
    if (grp < ntiles) {
        const unsigned short* Kt = Kh + (size_t)grp * KT * DK;
        const unsigned short* Vp = Vh + (size_t)grp * KT * DK;
        kr[0] = *(const u16x8*)(Kt + (size_t)srow0 * DK + sc8 * 8);
        vr[0] = *(const u16x8*)(Vp + (size_t)srow0 * DK + sc8 * 8);
        kr[1] = *(const u16x8*)(Kt + (size_t)srow1 * DK + sc8 * 8);
        vr[1] = *(const u16x8*)(Vp + (size_t)srow1 * DK + sc8 * 8);
    }

    for (int it = 0; it < npairs; ++it) {
        const int kt = 2 * it + grp;
        const bool act = kt < ntiles;
        __syncthreads();   // previous tile's LDS reads done
        if (act) {
            *(u16x8*)&Kg[srow0 * LDA + sc8 * 8] = kr[0];
            *(u16x8*)&Kg[srow1 * LDA + sc8 * 8] = kr[1];
#pragma unroll
            for (int e = 0; e < 8; ++e) {
                Vg[(sc8 * 8 + e) * LDA + (srow0 ^ (sc8 << 3))] = vr[0][e];
                Vg[(sc8 * 8 + e) * LDA + (srow1 ^ (sc8 << 3))] = vr[1][e];
            }
        }
        __syncthreads();

        // prefetch next tile for this group; hides under compute
        const int ktn = kt + 2;
        if (ktn < ntiles) {
            const unsigned short* Kn = Kh + (size_t)ktn * KT * DK;
            const unsigned short* Vn = Vh + (size_t)ktn * KT * DK;
            kr[0] = *(const u16x8*)(Kn + (size_t)srow0 * DK + sc8 * 8);
            vr[0] = *(const u16x8*)(Vn + (size_t)srow0 * DK + sc8 * 8);
            kr[1] = *(const u16x8*)(Kn + (size_t)srow1 * DK + sc8 * 8);
            vr[1] = *(const u16x8*)(Vn + (size_t)srow1 * DK + sc8 * 8);
        }
        if (!act) continue;   // no barriers below in loop body

        // S = Q K^T
        f32x4 sf[4];
        __builtin_amdgcn_s_setprio(1);
#pragma unroll
        for (int f = 0; f < 4; ++f) {
            u16x8 k0f = *(const u16x8*)&Kg[(f * 16 + l15) * LDA + ko];
            u16x8 k1f = *(const u16x8*)&Kg[(f * 16 + l15) * LDA + 32 + ko];
            f32x4 sv = (f32x4){0.f, 0.f, 0.f, 0.f};
            sv = mfma16(qf[0], k0f, sv);
            sv = mfma16(qf[1], k1f, sv);
            sf[f] = sv;
        }
        __builtin_amdgcn_s_setprio(0);

        // scale + causal mask (diagonal tile only)
        const bool diag = msk && (kt == ntiles - 1);
        float p_[4][4];
#pragma unroll
        for (int f = 0; f < 4; ++f) {
#pragma unroll
            for (int r = 0; r < 4; ++r) {
                float sv = sf[f][r] * 0.125f;
                if (diag && (f * 16 + l15 > qw * 16 + qlr + r)) sv = -1e30f;
                p_[f][r] = sv;
            }
        }

        // online softmax (rows live across 16 lanes sharing lane>>4)
        float alpha[4];
#pragma unroll
        for (int r = 0; r < 4; ++r) {
            float mt = fmaxf(fmaxf(p_[0][r], p_[1][r]), fmaxf(p_[2][r], p_[3][r]));
#pragma unroll
            for (int off = 1; off < 16; off <<= 1)
                mt = fmaxf(mt, __shfl_xor(mt, off, 64));
            float mn = fmaxf(m[r], mt);
            float al = __expf(m[r] - mn);
            float ls = 0.f;
#pragma unroll
            for (int f = 0; f < 4; ++f) {
                float p = __expf(p_[f][r] - mn);
                p_[f][r] = p;
                ls += p;
            }
#pragma unroll
            for (int off = 1; off < 16; off <<= 1)
                ls += __shfl_xor(ls, off, 64);
            m[r] = mn;
            l[r] = l[r] * al + ls;
            alpha[r] = al;
        }
#pragma unroll
        for (int d = 0; d < 4; ++d)
#pragma unroll
            for (int r = 0; r < 4; ++r)
                o[d][r] *= alpha[r];

        // P -> LDS (bf16), per-wave private region
#pragma unroll
        for (int f = 0; f < 4; ++f)
#pragma unroll
            for (int r = 0; r < 4; ++r)
                Pl[pbase + (qlr + r) * LDA + f * 16 + l15] = f2bf(p_[f][r]);

        // O += P V
        u16x8 pa0 = *(const u16x8*)&Pl[pbase + l15 * LDA + ko];
        u16x8 pa1 = *(const u16x8*)&Pl[pbase + l15 * LDA + 32 + ko];
        __builtin_amdgcn_s_setprio(1);
#pragma unroll
        for (int d = 0; d < 4; ++d) {
            int vd = d * 16 + l15;
            int sw = ((vd >> 3) & 7) << 3;
            u16x8 v0 = *(const u16x8*)&Vg[vd * LDA + (ko ^ sw)];
            u16x8 v1 = *(const u16x8*)&Vg[vd * LDA + ((ko + 32) ^ sw)];
            o[d] = mfma16(pa0, v0, o[d]);
            o[d] = mfma16(pa1, v1, o[d]);
        }
        __builtin_amdgcn_s_setprio(0);
    }

    // ---- merge the two groups' online-softmax states via LDS ----
    float* MB = (float*)Pl;   // 4608 floats available; need 4096 + 128
    __syncthreads();          // all loop work done
    if (grp == 1) {
        const int base = (qw * 64 + lane) * 16;
#pragma unroll
        for (int d = 0; d < 4; ++d)
#pragma unroll
            for (int r = 0; r < 4; ++r)
                MB[base + d * 4 + r] = o[d][r];
        if (l15 == 0) {
            const int mb = 4096 + (qw * 4 + (lane >> 4)) * 8;
#pragma unroll
            for (int r = 0; r < 4; ++r) {
                MB[mb + r]     = m[r];
                MB[mb + 4 + r] = l[r];
            }
        }
    }
    __syncthreads();
    if (grp == 0) {
        const int base = (qw * 64 + lane) * 16;
        const int mb = 4096 + (qw * 4 + (lane >> 4)) * 8;
#pragma unroll
        for (int r = 0; r < 4; ++r) {
            float m2 = MB[mb + r], l2 = MB[mb + 4 + r];
            float mn = fmaxf(m[r], m2);
            float ea = __expf(m[r] - mn);
            float eb = __expf(m2 - mn);
            float inv = 1.f / (l[r] * ea + l2 * eb);
            int row = q0 + qw * 16 + qlr + r;
            float* orow = out + ((size_t)(b * S_LEN + row)) * EMB + h * DK;
#pragma unroll
            for (int d = 0; d < 4; ++d)
                orow[d * 16 + l15] = (o[d][r] * ea + MB[base + d * 4 + r] * eb) * inv;
        }
    }
}

// ---------------------------------------------------------------- launch
extern "C" void kernel_launch(void* const* d_in, const int* in_sizes, int n_in,
                              void* d_out, int out_size, void* d_ws, size_t ws_size,
                              hipStream_t stream)
{
    const float* x  = (const float*)d_in[0];
    const float* wq = (const float*)d_in[1];
    const float* bq = (const float*)d_in[2];
    const float* wk = (const float*)d_in[3];
    const float* bk = (const float*)d_in[4];
    const float* wv = (const float*)d_in[5];
    const float* bv = (const float*)d_in[6];
    const int* msk  = (const int*)d_in[7];
    float* out = (float*)d_out;

    unsigned short* xb  = (unsigned short*)d_ws;              // 4096*1024
    unsigned short* wb  = xb + (size_t)M_TOT * EMB;           // 3*1024*1024
    unsigned short* qkv = wb + (size_t)3 * 1024 * 1024;       // 3*4194304

    cvt_kernel<<<7168, 256, 0, stream>>>(x, wq, wk, wv,
                                         xb, wb, wb + 1024 * 1024, wb + 2 * 1024 * 1024);
    qkv_gemm<<<dim3(8, 32, 3), 256, 0, stream>>>(xb, wb, bq, bk, bv, qkv);
    attn_kernel<<<dim3(32, 32, 1), 512, 0, stream>>>(
        qkv, qkv + (size_t)M_TOT * EMB, qkv + (size_t)2 * M_TOT * EMB, msk, out);
}

// Round 4
// 118.106 us; speedup vs baseline: 1.8885x; 1.1619x over previous
//
#include <hip/hip_runtime.h>

#define B_SZ   2
#define NH     16
#define S_LEN  2048
#define DK     64
#define EMB    1024
#define M_TOT  (B_SZ * S_LEN)   // 4096
#define KT     64

typedef float          f32x4  __attribute__((ext_vector_type(4)));
typedef float          f32x16 __attribute__((ext_vector_type(16)));
typedef unsigned int   u32x4  __attribute__((ext_vector_type(4)));
typedef unsigned short u16x8  __attribute__((ext_vector_type(8)));
typedef unsigned short u16x4  __attribute__((ext_vector_type(4)));
typedef __bf16         bf16x8 __attribute__((ext_vector_type(8)));

static __device__ __forceinline__ f32x4 mfma16(u16x8 a, u16x8 b, f32x4 c) {
    return __builtin_amdgcn_mfma_f32_16x16x32_bf16(
        __builtin_bit_cast(bf16x8, a), __builtin_bit_cast(bf16x8, b), c, 0, 0, 0);
}
static __device__ __forceinline__ f32x16 mfma32(u16x8 a, u16x8 b, f32x16 c) {
    return __builtin_amdgcn_mfma_f32_32x32x16_bf16(
        __builtin_bit_cast(bf16x8, a), __builtin_bit_cast(bf16x8, b), c, 0, 0, 0);
}

// round-to-nearest-even fp32 -> bf16 (finite inputs)
static __device__ __forceinline__ unsigned short f2bf(float f) {
    unsigned int u = __builtin_bit_cast(unsigned int, f);
    u = (u + 0x7FFFu + ((u >> 16) & 1u)) >> 16;
    return (unsigned short)u;
}

// ---------------------------------------------------------------- convert
__global__ __launch_bounds__(256) void cvt_kernel(
    const float* __restrict__ x,  const float* __restrict__ wq,
    const float* __restrict__ wk, const float* __restrict__ wv,
    unsigned short* __restrict__ xb,  unsigned short* __restrict__ wqb,
    unsigned short* __restrict__ wkb, unsigned short* __restrict__ wvb)
{
    long gid = (long)blockIdx.x * 256 + threadIdx.x;
    long e = gid * 4;
    const float* src; unsigned short* dst; long off;
    if      (e < 4194304L) { src = x;  dst = xb;  off = e; }
    else if (e < 5242880L) { src = wq; dst = wqb; off = e - 4194304L; }
    else if (e < 6291456L) { src = wk; dst = wkb; off = e - 5242880L; }
    else                   { src = wv; dst = wvb; off = e - 6291456L; }
    f32x4 v = *(const f32x4*)(src + off);
    u16x4 u;
    u[0] = f2bf(v[0]); u[1] = f2bf(v[1]); u[2] = f2bf(v[2]); u[3] = f2bf(v[3]);
    *(u16x4*)(dst + off) = u;
}

// ---------------------------------------------------------------- QKV GEMM
#define BM 128
#define BN 128
#define BK 64
#define LDK 72

__global__ __launch_bounds__(256) void qkv_gemm(
    const unsigned short* __restrict__ xb,
    const unsigned short* __restrict__ wb,
    const float* __restrict__ bq, const float* __restrict__ bk,
    const float* __restrict__ bv,
    unsigned short* __restrict__ qkv)
{
    const int tid  = threadIdx.x;
    const int lane = tid & 63;
    const int wid  = tid >> 6;
    const int wm   = wid >> 1, wn = wid & 1;
    const int n0   = blockIdx.x * BN;
    const int m0   = blockIdx.y * BM;
    const int mat  = blockIdx.z;

    const unsigned short* wmat = wb + (size_t)mat * (1024 * 1024);
    const float* bias = (mat == 0) ? bq : ((mat == 1) ? bk : bv);
    unsigned short* dst = qkv + (size_t)mat * ((size_t)M_TOT * EMB);

    __shared__ __align__(16) unsigned short Al[BM * LDK];
    __shared__ __align__(16) unsigned short Bl[BN * LDK];

    f32x4 acc[4][4];
#pragma unroll
    for (int i = 0; i < 4; ++i)
#pragma unroll
        for (int j = 0; j < 4; ++j)
            acc[i][j] = (f32x4){0.f, 0.f, 0.f, 0.f};

    for (int k0 = 0; k0 < EMB; k0 += BK) {
#pragma unroll
        for (int i = 0; i < 4; ++i) {
            int cc  = tid + i * 256;
            int row = cc >> 3, c8 = cc & 7;
            u16x8 va = *(const u16x8*)(xb   + (size_t)(m0 + row) * EMB + k0 + c8 * 8);
            *(u16x8*)&Al[row * LDK + c8 * 8] = va;
            u16x8 vb = *(const u16x8*)(wmat + (size_t)(n0 + row) * EMB + k0 + c8 * 8);
            *(u16x8*)&Bl[row * LDK + c8 * 8] = vb;
        }
        __syncthreads();

        const int ko = (lane >> 4) * 8;
#pragma unroll
        for (int kk = 0; kk < 2; ++kk) {
            u16x8 a[4], b[4];
#pragma unroll
            for (int i = 0; i < 4; ++i)
                a[i] = *(const u16x8*)&Al[(wm * 64 + i * 16 + (lane & 15)) * LDK + kk * 32 + ko];
#pragma unroll
            for (int j = 0; j < 4; ++j)
                b[j] = *(const u16x8*)&Bl[(wn * 64 + j * 16 + (lane & 15)) * LDK + kk * 32 + ko];
#pragma unroll
            for (int i = 0; i < 4; ++i)
#pragma unroll
                for (int j = 0; j < 4; ++j)
                    acc[i][j] = mfma16(a[i], b[j], acc[i][j]);
        }
        __syncthreads();
    }

#pragma unroll
    for (int j = 0; j < 4; ++j) {
        int n = n0 + wn * 64 + j * 16 + (lane & 15);
        float bvv = bias[n];
        int h = n >> 6, d = n & 63;
#pragma unroll
        for (int i = 0; i < 4; ++i) {
#pragma unroll
            for (int r = 0; r < 4; ++r) {
                int m = m0 + wm * 64 + i * 16 + ((lane >> 4) << 2) + r;
                int bb = m >> 11, s = m & 2047;
                dst[((size_t)((bb * NH + h) * S_LEN + s)) * DK + d] =
                    f2bf(acc[i][j][r] + bvv);
            }
        }
    }
}

// ---------------------------------------------------------------- attention
// 4 waves x 32 q-rows (QT=128). Swapped QK^T (32x32 MFMA): lane holds a full
// S^T column -> in-register softmax (2 shfls/tile). P^T -> B-fragment via
// cvt_pk_bf16 + permlane32_swap (no LDS roundtrip). O accumulated as O^T.
// K,V in LDS with XOR-swizzled linear [64][64] layouts (both sides swizzled).
__global__ __launch_bounds__(256) void attn_kernel(
    const unsigned short* __restrict__ Q,
    const unsigned short* __restrict__ K,
    const unsigned short* __restrict__ V,
    const int* __restrict__ mskp,
    float* __restrict__ out)
{
    const int tid = threadIdx.x, lane = tid & 63, qw = tid >> 6;
    const int l31 = lane & 31, H = lane >> 5;
    const int bh = blockIdx.x;
    const int h  = bh & 15, b = bh >> 4;
    const int y  = blockIdx.y;
    const int qt = (y < 8) ? y : 23 - y;   // diagonal map: pairs (y,y+8) sum to 15
    const int q0 = qt * 128;
    const size_t hoff = ((size_t)(b * NH + h)) * S_LEN * DK;
    const unsigned short* Qh = Q + hoff;
    const unsigned short* Kh = K + hoff;
    const unsigned short* Vh = V + hoff;
    const int msk = *mskp;
    const int ntiles = msk ? (2 * qt + 2) : (S_LEN / KT);

    __shared__ __align__(16) unsigned short Kl[64 * 64];  // [k][d], d-granule ^ (k&7)
    __shared__ __align__(16) unsigned short Vt[64 * 64];  // [d][k], k-granule ^ (d>>3)

    const int qrow = q0 + qw * 32 + l31;
    u16x8 qf[4];
#pragma unroll
    for (int ks = 0; ks < 4; ++ks)
        qf[ks] = *(const u16x8*)(Qh + (size_t)qrow * DK + ks * 16 + H * 8);

    f32x16 o0, o1;
#pragma unroll
    for (int i = 0; i < 16; ++i) { o0[i] = 0.f; o1[i] = 0.f; }
    float mx = -1e30f, lsum = 0.f;

    const int sr0 = tid >> 3, sc8 = tid & 7, sr1 = sr0 + 32;
    const int kwo0 = sr0 * 64 + ((sc8 ^ (sr0 & 7)) << 3);
    const int kwo1 = sr1 * 64 + ((sc8 ^ (sr1 & 7)) << 3);
    const int vwo0 = (((sr0 >> 3) ^ sc8) << 3) + (sr0 & 7);
    const int vwo1 = (((sr1 >> 3) ^ sc8) << 3) + (sr1 & 7);

    u16x8 kr[2], vr[2];
    kr[0] = *(const u16x8*)(Kh + (size_t)sr0 * DK + sc8 * 8);
    vr[0] = *(const u16x8*)(Vh + (size_t)sr0 * DK + sc8 * 8);
    kr[1] = *(const u16x8*)(Kh + (size_t)sr1 * DK + sc8 * 8);
    vr[1] = *(const u16x8*)(Vh + (size_t)sr1 * DK + sc8 * 8);

    const int qmin = q0 + qw * 32;
    const int dsw0 = l31 >> 3, dsw1 = 4 + (l31 >> 3);
    const int rsw  = l31 & 7;

    for (int kt = 0; kt < ntiles; ++kt) {
        __syncthreads();   // readers done with LDS
        *(u16x8*)&Kl[kwo0] = kr[0];
        *(u16x8*)&Kl[kwo1] = kr[1];
#pragma unroll
        for (int e = 0; e < 8; ++e) {
            Vt[(sc8 * 8 + e) * 64 + vwo0] = vr[0][e];
            Vt[(sc8 * 8 + e) * 64 + vwo1] = vr[1][e];
        }
        __syncthreads();

        if (kt + 1 < ntiles) {   // prefetch next tile (hides under compute)
            const unsigned short* Kn = Kh + (size_t)(kt + 1) * KT * DK;
            const unsigned short* Vn = Vh + (size_t)(kt + 1) * KT * DK;
            kr[0] = *(const u16x8*)(Kn + (size_t)sr0 * DK + sc8 * 8);
            vr[0] = *(const u16x8*)(Vn + (size_t)sr0 * DK + sc8 * 8);
            kr[1] = *(const u16x8*)(Kn + (size_t)sr1 * DK + sc8 * 8);
            vr[1] = *(const u16x8*)(Vn + (size_t)sr1 * DK + sc8 * 8);
        }

        if (msk && kt * KT > qmin + 31) continue;  // wave-uniform; barriers above

        // ---- S^T = K Q^T : lane holds q-col = l31, k-rows per (H, reg) ----
        f32x16 st0, st1;
#pragma unroll
        for (int i = 0; i < 16; ++i) { st0[i] = 0.f; st1[i] = 0.f; }
        __builtin_amdgcn_s_setprio(1);
#pragma unroll
        for (int ks = 0; ks < 4; ++ks) {
            const int g = (((ks << 1) + H) ^ rsw) << 3;
            u16x8 kf0 = *(const u16x8*)&Kl[l31 * 64 + g];
            u16x8 kf1 = *(const u16x8*)&Kl[(32 + l31) * 64 + g];
            st0 = mfma32(kf0, qf[ks], st0);
            st1 = mfma32(kf1, qf[ks], st1);
        }
        __builtin_amdgcn_s_setprio(0);

        // ---- scale + causal mask (register-side) ----
        const bool needmask = msk && (kt * KT + 63 > qrow);
        float p[32];
#pragma unroll
        for (int r = 0; r < 16; ++r) {
            const int krow = (r & 3) + 8 * (r >> 2) + 4 * H;
            float v0 = st0[r] * 0.125f;
            float v1 = st1[r] * 0.125f;
            if (needmask) {
                if (kt * KT + krow > qrow)      v0 = -1e30f;
                if (kt * KT + 32 + krow > qrow) v1 = -1e30f;
            }
            p[r] = v0; p[16 + r] = v1;
        }

        // ---- online softmax: in-register tree + one shfl(32) ----
        float t8[8];
#pragma unroll
        for (int i = 0; i < 8; ++i)
            t8[i] = fmaxf(fmaxf(p[i], p[i + 8]), fmaxf(p[i + 16], p[i + 24]));
#pragma unroll
        for (int i = 0; i < 4; ++i) t8[i] = fmaxf(t8[i], t8[i + 4]);
        float mt = fmaxf(fmaxf(t8[0], t8[1]), fmaxf(t8[2], t8[3]));
        mt = fmaxf(mt, __shfl_xor(mt, 32, 64));
        const float mn = fmaxf(mx, mt);
        const float al = __expf(mx - mn);
        mx = mn;

        float s8[8];
#pragma unroll
        for (int i = 0; i < 8; ++i) s8[i] = 0.f;
#pragma unroll
        for (int r = 0; r < 32; ++r) {
            p[r] = __expf(p[r] - mn);
            s8[r & 7] += p[r];
        }
        float ls = ((s8[0] + s8[1]) + (s8[2] + s8[3])) +
                   ((s8[4] + s8[5]) + (s8[6] + s8[7]));
        ls += __shfl_xor(ls, 32, 64);
        lsum = lsum * al + ls;
#pragma unroll
        for (int i = 0; i < 16; ++i) { o0[i] *= al; o1[i] *= al; }

        // ---- P^T -> bf16 B-fragments (cvt_pk + permlane32_swap), then PV ----
        __builtin_amdgcn_s_setprio(1);
#pragma unroll
        for (int ks = 0; ks < 4; ++ks) {
            const int bb = ks * 8;
            unsigned int wa, wb2, wc, wd;
            asm("v_cvt_pk_bf16_f32 %0, %1, %2" : "=v"(wa)  : "v"(p[bb + 0]), "v"(p[bb + 1]));
            asm("v_cvt_pk_bf16_f32 %0, %1, %2" : "=v"(wb2) : "v"(p[bb + 2]), "v"(p[bb + 3]));
            asm("v_cvt_pk_bf16_f32 %0, %1, %2" : "=v"(wc)  : "v"(p[bb + 4]), "v"(p[bb + 5]));
            asm("v_cvt_pk_bf16_f32 %0, %1, %2" : "=v"(wd)  : "v"(p[bb + 6]), "v"(p[bb + 7]));
            asm volatile("v_permlane32_swap_b32 %0, %1" : "+v"(wa),  "+v"(wc));
            asm volatile("v_permlane32_swap_b32 %0, %1" : "+v"(wb2), "+v"(wd));
            u32x4 wv; wv[0] = wa; wv[1] = wb2; wv[2] = wc; wv[3] = wd;
            const u16x8 pb = __builtin_bit_cast(u16x8, wv);
            const int kg = (ks << 1) + H;
            u16x8 vf0 = *(const u16x8*)&Vt[l31 * 64        + ((kg ^ dsw0) << 3)];
            u16x8 vf1 = *(const u16x8*)&Vt[(32 + l31) * 64 + ((kg ^ dsw1) << 3)];
            o0 = mfma32(vf0, pb, o0);
            o1 = mfma32(vf1, pb, o1);
        }
        __builtin_amdgcn_s_setprio(0);
    }

    // ---- epilogue: O^T regs -> out rows (q = l31 col; d consecutive by 4) ----
    const float inv = 1.f / lsum;
    float* orow = out + ((size_t)(b * S_LEN) + qrow) * EMB + h * DK;
#pragma unroll
    for (int g = 0; g < 4; ++g) {
        f32x4 w0, w1;
#pragma unroll
        for (int i = 0; i < 4; ++i) { w0[i] = o0[4 * g + i] * inv; w1[i] = o1[4 * g + i] * inv; }
        *(f32x4*)&orow[8 * g + 4 * H]      = w0;
        *(f32x4*)&orow[32 + 8 * g + 4 * H] = w1;
    }
}

// ---------------------------------------------------------------- launch
extern "C" void kernel_launch(void* const* d_in, const int* in_sizes, int n_in,
                              void* d_out, int out_size, void* d_ws, size_t ws_size,
                              hipStream_t stream)
{
    const float* x  = (const float*)d_in[0];
    const float* wq = (const float*)d_in[1];
    const float* bq = (const float*)d_in[2];
    const float* wk = (const float*)d_in[3];
    const float* bk = (const float*)d_in[4];
    const float* wv = (const float*)d_in[5];
    const float* bv = (const float*)d_in[6];
    const int* msk  = (const int*)d_in[7];
    float* out = (float*)d_out;

    unsigned short* xb  = (unsigned short*)d_ws;
    unsigned short* wb  = xb + (size_t)M_TOT * EMB;
    unsigned short* qkv = wb + (size_t)3 * 1024 * 1024;

    cvt_kernel<<<7168, 256, 0, stream>>>(x, wq, wk, wv,
                                         xb, wb, wb + 1024 * 1024, wb + 2 * 1024 * 1024);
    qkv_gemm<<<dim3(8, 32, 3), 256, 0, stream>>>(xb, wb, bq, bk, bv, qkv);
    attn_kernel<<<dim3(32, 16, 1), 256, 0, stream>>>(
        qkv, qkv + (size_t)M_TOT * EMB, qkv + (size_t)2 * M_TOT * EMB, msk, out);
}

// Round 6
// 108.780 us; speedup vs baseline: 2.0505x; 1.0857x over previous
//
#include <hip/hip_runtime.h>

#define B_SZ   2
#define NH     16
#define S_LEN  2048
#define DK     64
#define EMB    1024
#define M_TOT  (B_SZ * S_LEN)   // 4096
#define KT     64

typedef float          f32x4  __attribute__((ext_vector_type(4)));
typedef float          f32x16 __attribute__((ext_vector_type(16)));
typedef unsigned int   u32x4  __attribute__((ext_vector_type(4)));
typedef unsigned short u16x8  __attribute__((ext_vector_type(8)));
typedef unsigned short u16x4  __attribute__((ext_vector_type(4)));
typedef __bf16         bf16x8 __attribute__((ext_vector_type(8)));

static __device__ __forceinline__ f32x4 mfma16(u16x8 a, u16x8 b, f32x4 c) {
    return __builtin_amdgcn_mfma_f32_16x16x32_bf16(
        __builtin_bit_cast(bf16x8, a), __builtin_bit_cast(bf16x8, b), c, 0, 0, 0);
}
static __device__ __forceinline__ f32x16 mfma32(u16x8 a, u16x8 b, f32x16 c) {
    return __builtin_amdgcn_mfma_f32_32x32x16_bf16(
        __builtin_bit_cast(bf16x8, a), __builtin_bit_cast(bf16x8, b), c, 0, 0, 0);
}

// round-to-nearest-even fp32 -> bf16 (finite inputs)
static __device__ __forceinline__ unsigned short f2bf(float f) {
    unsigned int u = __builtin_bit_cast(unsigned int, f);
    u = (u + 0x7FFFu + ((u >> 16) & 1u)) >> 16;
    return (unsigned short)u;
}

// hardware 2^x
static __device__ __forceinline__ float exp2_hw(float x) {
    float r; asm("v_exp_f32 %0, %1" : "=v"(r) : "v"(x)); return r;
}

// async global -> LDS, 16B per lane; LDS dest = uniform base + lane*16
#define GLDS16(g, l)  __builtin_amdgcn_global_load_lds(                      \
    (const void __attribute__((address_space(1)))*)(g),                      \
    (void __attribute__((address_space(3)))*)(l), 16, 0, 0)

// ---------------------------------------------------------------- convert
__global__ __launch_bounds__(256) void cvt_kernel(
    const float* __restrict__ x,  const float* __restrict__ wq,
    const float* __restrict__ wk, const float* __restrict__ wv,
    unsigned short* __restrict__ xb,  unsigned short* __restrict__ wqb,
    unsigned short* __restrict__ wkb, unsigned short* __restrict__ wvb)
{
    long gid = (long)blockIdx.x * 256 + threadIdx.x;
    long e = gid * 4;
    const float* src; unsigned short* dst; long off;
    if      (e < 4194304L) { src = x;  dst = xb;  off = e; }
    else if (e < 5242880L) { src = wq; dst = wqb; off = e - 4194304L; }
    else if (e < 6291456L) { src = wk; dst = wkb; off = e - 5242880L; }
    else                   { src = wv; dst = wvb; off = e - 6291456L; }
    f32x4 v = *(const f32x4*)(src + off);
    u16x4 u;
    u[0] = f2bf(v[0]); u[1] = f2bf(v[1]); u[2] = f2bf(v[2]); u[3] = f2bf(v[3]);
    *(u16x4*)(dst + off) = u;
}

// ---------------------------------------------------------------- QKV GEMM
// m97 template: global_load_lds width-16 staging, linear [row][64] LDS.
#define BM 128
#define BN 128
#define BK 64

__global__ __launch_bounds__(256) void qkv_gemm(
    const unsigned short* __restrict__ xb,
    const unsigned short* __restrict__ wb,
    const float* __restrict__ bq, const float* __restrict__ bk,
    const float* __restrict__ bv,
    unsigned short* __restrict__ qkv)
{
    const int tid  = threadIdx.x;
    const int lane = tid & 63;
    const int wid  = tid >> 6;
    const int wm   = wid >> 1, wn = wid & 1;
    const int n0   = blockIdx.x * BN;
    const int m0   = blockIdx.y * BM;
    const int mat  = blockIdx.z;

    const unsigned short* wmat = wb + (size_t)mat * (1024 * 1024);
    const float* bias = (mat == 0) ? bq : ((mat == 1) ? bk : bv);
    unsigned short* dst = qkv + (size_t)mat * ((size_t)M_TOT * EMB);

    __shared__ __align__(16) unsigned short Al[BM * 64];
    __shared__ __align__(16) unsigned short Bl[BN * 64];

    f32x4 acc[4][4];
#pragma unroll
    for (int i = 0; i < 4; ++i)
#pragma unroll
        for (int j = 0; j < 4; ++j)
            acc[i][j] = (f32x4){0.f, 0.f, 0.f, 0.f};

    const int wrow = wid * 32;                   // wave's staging row block
    const int lrow = lane >> 3, lcol = (lane & 7) * 8;
    const int l15  = lane & 15;
    const int ko   = (lane >> 4) * 8;

    for (int k0 = 0; k0 < EMB; k0 += BK) {
        const unsigned short* ga = xb   + (size_t)(m0 + wrow + lrow) * EMB + k0 + lcol;
        const unsigned short* gb = wmat + (size_t)(n0 + wrow + lrow) * EMB + k0 + lcol;
#pragma unroll
        for (int j = 0; j < 4; ++j) {
            GLDS16(ga + (size_t)j * 8 * EMB, &Al[(wrow + j * 8) * 64]);
            GLDS16(gb + (size_t)j * 8 * EMB, &Bl[(wrow + j * 8) * 64]);
        }
        __syncthreads();     // drains vmcnt -> staged tile visible

#pragma unroll
        for (int kk = 0; kk < 2; ++kk) {
            u16x8 a[4], b[4];
#pragma unroll
            for (int i = 0; i < 4; ++i)
                a[i] = *(const u16x8*)&Al[(wm * 64 + i * 16 + l15) * 64 + kk * 32 + ko];
#pragma unroll
            for (int j = 0; j < 4; ++j)
                b[j] = *(const u16x8*)&Bl[(wn * 64 + j * 16 + l15) * 64 + kk * 32 + ko];
#pragma unroll
            for (int i = 0; i < 4; ++i)
#pragma unroll
                for (int j = 0; j < 4; ++j)
                    acc[i][j] = mfma16(a[i], b[j], acc[i][j]);
        }
        __syncthreads();
    }

#pragma unroll
    for (int j = 0; j < 4; ++j) {
        int n = n0 + wn * 64 + j * 16 + l15;
        float bvv = bias[n];
        int h = n >> 6, d = n & 63;
#pragma unroll
        for (int i = 0; i < 4; ++i) {
#pragma unroll
            for (int r = 0; r < 4; ++r) {
                int m = m0 + wm * 64 + i * 16 + ((lane >> 4) << 2) + r;
                int bb = m >> 11, s = m & 2047;
                dst[((size_t)((bb * NH + h) * S_LEN + s)) * DK + d] =
                    f2bf(acc[i][j][r] + bvv);
            }
        }
    }
}

// ---------------------------------------------------------------- attention
// 8 waves: 4 q-waves (32 rows each, QT=128) x 2 K-parity groups (even/odd
// K-tiles, group-private LDS, LSE merge at end).  Swapped QK^T (32x32 MFMA),
// in-register exp2-domain softmax with defer-max, cvt_pk+permlane32 P->B.
__global__ __launch_bounds__(512) void attn_kernel(
    const unsigned short* __restrict__ Q,
    const unsigned short* __restrict__ K,
    const unsigned short* __restrict__ V,
    const int* __restrict__ mskp,
    float* __restrict__ out)
{
    const int tid = threadIdx.x, lane = tid & 63, wid = tid >> 6;
    const int grp = wid >> 2, qw = wid & 3;
    const int l31 = lane & 31, H = lane >> 5;
    const int bh = blockIdx.x;
    const int h  = bh & 15, b = bh >> 4;
    const int y  = blockIdx.y;
    const int qt = (y < 8) ? y : 23 - y;   // pairs (y,y+8): qt sums to 15
    const int q0 = qt * 128;
    const size_t hoff = ((size_t)(b * NH + h)) * S_LEN * DK;
    const unsigned short* Qh = Q + hoff;
    const unsigned short* Kh = K + hoff;
    const unsigned short* Vh = V + hoff;
    const int msk = *mskp;
    const int ntiles = msk ? (2 * qt + 2) : (S_LEN / KT);  // always even
    const int niter  = ntiles >> 1;

    __shared__ __align__(16) unsigned short Kl[2][64 * 64];
    __shared__ __align__(16) unsigned short Vt[2][64 * 64];
    __shared__ float MLbuf[512];           // merge m/l pairs (separate!)
    unsigned short* Kg = Kl[grp];
    unsigned short* Vg = Vt[grp];

    const int qrow = q0 + qw * 32 + l31;
    u16x8 qf[4];
#pragma unroll
    for (int ks = 0; ks < 4; ++ks)
        qf[ks] = *(const u16x8*)(Qh + (size_t)qrow * DK + ks * 16 + H * 8);

    f32x16 o0, o1;
#pragma unroll
    for (int i = 0; i < 16; ++i) { o0[i] = 0.f; o1[i] = 0.f; }
    float mx = -1e30f, lsum = 0.f;

    const int gt  = tid & 255;              // thread within group
    const int sr0 = gt >> 3, sc8 = gt & 7, sr1 = sr0 + 32;
    const int kwo0 = sr0 * 64 + ((sc8 ^ (sr0 & 7)) << 3);
    const int kwo1 = sr1 * 64 + ((sc8 ^ (sr1 & 7)) << 3);
    const int vwo0 = (((sr0 >> 3) ^ sc8) << 3) + (sr0 & 7);
    const int vwo1 = (((sr1 >> 3) ^ sc8) << 3) + (sr1 & 7);

    u16x8 kr[2], vr[2];
    {
        const unsigned short* K0 = Kh + (size_t)grp * KT * DK;
        const unsigned short* V0 = Vh + (size_t)grp * KT * DK;
        kr[0] = *(const u16x8*)(K0 + (size_t)sr0 * DK + sc8 * 8);
        vr[0] = *(const u16x8*)(V0 + (size_t)sr0 * DK + sc8 * 8);
        kr[1] = *(const u16x8*)(K0 + (size_t)sr1 * DK + sc8 * 8);
        vr[1] = *(const u16x8*)(V0 + (size_t)sr1 * DK + sc8 * 8);
    }

    const int qmin = q0 + qw * 32;
    const int dsw0 = l31 >> 3, dsw1 = 4 + (l31 >> 3);
    const int rsw  = l31 & 7;
    const float SC2 = 0.125f * 1.4426950408889634f;   // fold log2(e)

    for (int it = 0; it < niter; ++it) {
        const int kt = 2 * it + grp;
        __syncthreads();   // group's readers done with its LDS tile
        *(u16x8*)&Kg[kwo0] = kr[0];
        *(u16x8*)&Kg[kwo1] = kr[1];
#pragma unroll
        for (int e = 0; e < 8; ++e) {
            Vg[(sc8 * 8 + e) * 64 + vwo0] = vr[0][e];
            Vg[(sc8 * 8 + e) * 64 + vwo1] = vr[1][e];
        }
        __syncthreads();

        if (it + 1 < niter) {   // prefetch this group's next tile
            const unsigned short* Kn = Kh + (size_t)(kt + 2) * KT * DK;
            const unsigned short* Vn = Vh + (size_t)(kt + 2) * KT * DK;
            kr[0] = *(const u16x8*)(Kn + (size_t)sr0 * DK + sc8 * 8);
            vr[0] = *(const u16x8*)(Vn + (size_t)sr0 * DK + sc8 * 8);
            kr[1] = *(const u16x8*)(Kn + (size_t)sr1 * DK + sc8 * 8);
            vr[1] = *(const u16x8*)(Vn + (size_t)sr1 * DK + sc8 * 8);
        }

        if (msk && kt * KT > qmin + 31) continue;  // wave-uniform skip

        // ---- S^T = K Q^T ----
        f32x16 st0, st1;
#pragma unroll
        for (int i = 0; i < 16; ++i) { st0[i] = 0.f; st1[i] = 0.f; }
        __builtin_amdgcn_s_setprio(1);
#pragma unroll
        for (int ks = 0; ks < 4; ++ks) {
            const int g = (((ks << 1) + H) ^ rsw) << 3;
            u16x8 kf0 = *(const u16x8*)&Kg[l31 * 64 + g];
            u16x8 kf1 = *(const u16x8*)&Kg[(32 + l31) * 64 + g];
            st0 = mfma32(kf0, qf[ks], st0);
            st1 = mfma32(kf1, qf[ks], st1);
        }
        __builtin_amdgcn_s_setprio(0);

        // ---- scale (exp2 domain) + causal mask ----
        const bool needmask = msk && (kt * KT + 63 > qrow);
        float p[32];
#pragma unroll
        for (int r = 0; r < 16; ++r) {
            const int krow = (r & 3) + 8 * (r >> 2) + 4 * H;
            float v0 = st0[r] * SC2;
            float v1 = st1[r] * SC2;
            if (needmask) {
                if (kt * KT + krow > qrow)      v0 = -1e30f;
                if (kt * KT + 32 + krow > qrow) v1 = -1e30f;
            }
            p[r] = v0; p[16 + r] = v1;
        }

        // ---- online softmax: register tree + one shfl(32); defer-max ----
        float t8[8];
#pragma unroll
        for (int i = 0; i < 8; ++i)
            t8[i] = fmaxf(fmaxf(p[i], p[i + 8]), fmaxf(p[i + 16], p[i + 24]));
#pragma unroll
        for (int i = 0; i < 4; ++i) t8[i] = fmaxf(t8[i], t8[i + 4]);
        float mt = fmaxf(fmaxf(t8[0], t8[1]), fmaxf(t8[2], t8[3]));
        mt = fmaxf(mt, __shfl_xor(mt, 32, 64));

        if (!__all(mt <= mx + 11.54f)) {   // 8 nats in log2 domain
            const float mn = fmaxf(mx, mt);
            const float al = exp2_hw(mx - mn);
            mx = mn;
            lsum *= al;
#pragma unroll
            for (int i = 0; i < 16; ++i) { o0[i] *= al; o1[i] *= al; }
        }

        float s8[8];
#pragma unroll
        for (int i = 0; i < 8; ++i) s8[i] = 0.f;
#pragma unroll
        for (int r = 0; r < 32; ++r) {
            p[r] = exp2_hw(p[r] - mx);
            s8[r & 7] += p[r];
        }
        float ls = ((s8[0] + s8[1]) + (s8[2] + s8[3])) +
                   ((s8[4] + s8[5]) + (s8[6] + s8[7]));
        ls += __shfl_xor(ls, 32, 64);
        lsum += ls;

        // ---- P^T -> bf16 B-fragments, then PV ----
        __builtin_amdgcn_s_setprio(1);
#pragma unroll
        for (int ks = 0; ks < 4; ++ks) {
            const int bb = ks * 8;
            unsigned int wa, wb2, wc, wd;
            asm("v_cvt_pk_bf16_f32 %0, %1, %2" : "=v"(wa)  : "v"(p[bb + 0]), "v"(p[bb + 1]));
            asm("v_cvt_pk_bf16_f32 %0, %1, %2" : "=v"(wb2) : "v"(p[bb + 2]), "v"(p[bb + 3]));
            asm("v_cvt_pk_bf16_f32 %0, %1, %2" : "=v"(wc)  : "v"(p[bb + 4]), "v"(p[bb + 5]));
            asm("v_cvt_pk_bf16_f32 %0, %1, %2" : "=v"(wd)  : "v"(p[bb + 6]), "v"(p[bb + 7]));
            asm volatile("v_permlane32_swap_b32 %0, %1" : "+v"(wa),  "+v"(wc));
            asm volatile("v_permlane32_swap_b32 %0, %1" : "+v"(wb2), "+v"(wd));
            u32x4 wv; wv[0] = wa; wv[1] = wb2; wv[2] = wc; wv[3] = wd;
            const u16x8 pb = __builtin_bit_cast(u16x8, wv);
            const int kg = (ks << 1) + H;
            u16x8 vf0 = *(const u16x8*)&Vg[l31 * 64        + ((kg ^ dsw0) << 3)];
            u16x8 vf1 = *(const u16x8*)&Vg[(32 + l31) * 64 + ((kg ^ dsw1) << 3)];
            o0 = mfma32(vf0, pb, o0);
            o1 = mfma32(vf1, pb, o1);
        }
        __builtin_amdgcn_s_setprio(0);
    }

    // ---- merge group 0 + group 1 (LSE combine) ----
    // MO: 256 rows x 32 floats = 32 KB, split exactly across Kl (idx<128)
    // and Vt (idx>=128); m/l pairs live in the separate MLbuf.
    const int idx = qw * 64 + lane;
    float* MO = (idx < 128) ? ((float*)Kl + idx * 32)
                            : ((float*)Vt + (idx - 128) * 32);
    __syncthreads();
    if (grp == 1) {
#pragma unroll
        for (int i = 0; i < 16; ++i) {
            MO[(i + idx) & 31]      = o0[i];
            MO[(16 + i + idx) & 31] = o1[i];
        }
        MLbuf[idx * 2]     = mx;
        MLbuf[idx * 2 + 1] = lsum;
    }
    __syncthreads();
    if (grp == 0) {
        const float m2 = MLbuf[idx * 2], l2 = MLbuf[idx * 2 + 1];
        const float mn = fmaxf(mx, m2);
        const float ea = exp2_hw(mx - mn);
        const float eb = exp2_hw(m2 - mn);
        const float inv = 1.f / (lsum * ea + l2 * eb);
        float* orow = out + ((size_t)(b * S_LEN) + qrow) * EMB + h * DK;
#pragma unroll
        for (int g = 0; g < 4; ++g) {
            f32x4 w0, w1;
#pragma unroll
            for (int i = 0; i < 4; ++i) {
                w0[i] = (o0[4 * g + i] * ea + MO[(4 * g + i + idx) & 31] * eb) * inv;
                w1[i] = (o1[4 * g + i] * ea + MO[(16 + 4 * g + i + idx) & 31] * eb) * inv;
            }
            *(f32x4*)&orow[8 * g + 4 * H]      = w0;
            *(f32x4*)&orow[32 + 8 * g + 4 * H] = w1;
        }
    }
}

// ---------------------------------------------------------------- launch
extern "C" void kernel_launch(void* const* d_in, const int* in_sizes, int n_in,
                              void* d_out, int out_size, void* d_ws, size_t ws_size,
                              hipStream_t stream)
{
    const float* x  = (const float*)d_in[0];
    const float* wq = (const float*)d_in[1];
    const float* bq = (const float*)d_in[2];
    const float* wk = (const float*)d_in[3];
    const float* bk = (const float*)d_in[4];
    const float* wv = (const float*)d_in[5];
    const float* bv = (const float*)d_in[6];
    const int* msk  = (const int*)d_in[7];
    float* out = (float*)d_out;

    unsigned short* xb  = (unsigned short*)d_ws;
    unsigned short* wb  = xb + (size_t)M_TOT * EMB;
    unsigned short* qkv = wb + (size_t)3 * 1024 * 1024;

    cvt_kernel<<<7168, 256, 0, stream>>>(x, wq, wk, wv,
                                         xb, wb, wb + 1024 * 1024, wb + 2 * 1024 * 1024);
    qkv_gemm<<<dim3(8, 32, 3), 256, 0, stream>>>(xb, wb, bq, bk, bv, qkv);
    attn_kernel<<<dim3(32, 16, 1), 512, 0, stream>>>(
        qkv, qkv + (size_t)M_TOT * EMB, qkv + (size_t)2 * M_TOT * EMB, msk, out);
}

// Round 7
// 95.977 us; speedup vs baseline: 2.3240x; 1.1334x over previous
//
#include <hip/hip_runtime.h>

#define B_SZ   2
#define NH     16
#define S_LEN  2048
#define DK     64
#define EMB    1024
#define M_TOT  (B_SZ * S_LEN)   // 4096
#define KT     64

typedef float          f32x4  __attribute__((ext_vector_type(4)));
typedef float          f32x16 __attribute__((ext_vector_type(16)));
typedef unsigned int   u32x4  __attribute__((ext_vector_type(4)));
typedef unsigned short u16x8  __attribute__((ext_vector_type(8)));
typedef unsigned short u16x4  __attribute__((ext_vector_type(4)));
typedef __bf16         bf16x8 __attribute__((ext_vector_type(8)));

static __device__ __forceinline__ f32x4 mfma16(u16x8 a, u16x8 b, f32x4 c) {
    return __builtin_amdgcn_mfma_f32_16x16x32_bf16(
        __builtin_bit_cast(bf16x8, a), __builtin_bit_cast(bf16x8, b), c, 0, 0, 0);
}
static __device__ __forceinline__ f32x16 mfma32(u16x8 a, u16x8 b, f32x16 c) {
    return __builtin_amdgcn_mfma_f32_32x32x16_bf16(
        __builtin_bit_cast(bf16x8, a), __builtin_bit_cast(bf16x8, b), c, 0, 0, 0);
}

// round-to-nearest-even fp32 -> bf16 (finite inputs)
static __device__ __forceinline__ unsigned short f2bf(float f) {
    unsigned int u = __builtin_bit_cast(unsigned int, f);
    u = (u + 0x7FFFu + ((u >> 16) & 1u)) >> 16;
    return (unsigned short)u;
}

// hardware 2^x
static __device__ __forceinline__ float exp2_hw(float x) {
    float r; asm("v_exp_f32 %0, %1" : "=v"(r) : "v"(x)); return r;
}

// async global -> LDS, 16B per lane; LDS dest = uniform base + lane*16
#define GLDS16(g, l)  __builtin_amdgcn_global_load_lds(                      \
    (const void __attribute__((address_space(1)))*)(g),                      \
    (void __attribute__((address_space(3)))*)(l), 16, 0, 0)

// ---------------------------------------------------------------- convert
__global__ __launch_bounds__(256) void cvt_kernel(
    const float* __restrict__ x,  const float* __restrict__ wq,
    const float* __restrict__ wk, const float* __restrict__ wv,
    unsigned short* __restrict__ xb,  unsigned short* __restrict__ wqb,
    unsigned short* __restrict__ wkb, unsigned short* __restrict__ wvb)
{
    long gid = (long)blockIdx.x * 256 + threadIdx.x;
    long e = gid * 4;
    const float* src; unsigned short* dst; long off;
    if      (e < 4194304L) { src = x;  dst = xb;  off = e; }
    else if (e < 5242880L) { src = wq; dst = wqb; off = e - 4194304L; }
    else if (e < 6291456L) { src = wk; dst = wkb; off = e - 5242880L; }
    else                   { src = wv; dst = wvb; off = e - 6291456L; }
    f32x4 v = *(const f32x4*)(src + off);
    u16x4 u;
    u[0] = f2bf(v[0]); u[1] = f2bf(v[1]); u[2] = f2bf(v[2]); u[3] = f2bf(v[3]);
    *(u16x4*)(dst + off) = u;
}

// ---------------------------------------------------------------- QKV GEMM
// m97 template + both-sides XOR swizzle (rule #21):
//   LDS linear [row][64]; global SOURCE pre-swizzled so LDS(row, slot) holds
//   global slot (slot ^ (row&7)); fragment read XORs slot with (l15&7).
#define BM 128
#define BN 128
#define BK 64

__global__ __launch_bounds__(256) void qkv_gemm(
    const unsigned short* __restrict__ xb,
    const unsigned short* __restrict__ wb,
    const float* __restrict__ bq, const float* __restrict__ bk,
    const float* __restrict__ bv,
    unsigned short* __restrict__ qkv)
{
    const int tid  = threadIdx.x;
    const int lane = tid & 63;
    const int wid  = tid >> 6;
    const int wm   = wid >> 1, wn = wid & 1;
    const int n0   = blockIdx.x * BN;
    const int m0   = blockIdx.y * BM;
    const int mat  = blockIdx.z;

    const unsigned short* wmat = wb + (size_t)mat * (1024 * 1024);
    const float* bias = (mat == 0) ? bq : ((mat == 1) ? bk : bv);
    unsigned short* dst = qkv + (size_t)mat * ((size_t)M_TOT * EMB);

    __shared__ __align__(16) unsigned short Al[BM * 64];
    __shared__ __align__(16) unsigned short Bl[BN * 64];

    f32x4 acc[4][4];
#pragma unroll
    for (int i = 0; i < 4; ++i)
#pragma unroll
        for (int j = 0; j < 4; ++j)
            acc[i][j] = (f32x4){0.f, 0.f, 0.f, 0.f};

    const int wrow = wid * 32;                    // wave's staging row block
    const int lrow = lane >> 3;                   // row within 8-row stripe
    const int lcol = ((lane & 7) ^ lrow) * 8;     // PRE-SWIZZLED source slot
    const int l15  = lane & 15;
    // fragment-read slots (slot = (kk*4 + lane>>4) ^ (row&7), row&7 = l15&7)
    const int sl0 = (((lane >> 4))     ^ (l15 & 7)) * 8;   // kk = 0
    const int sl1 = ((4 + (lane >> 4)) ^ (l15 & 7)) * 8;   // kk = 1

    for (int k0 = 0; k0 < EMB; k0 += BK) {
        const unsigned short* ga = xb   + (size_t)(m0 + wrow + lrow) * EMB + k0 + lcol;
        const unsigned short* gb = wmat + (size_t)(n0 + wrow + lrow) * EMB + k0 + lcol;
#pragma unroll
        for (int j = 0; j < 4; ++j) {
            GLDS16(ga + (size_t)j * 8 * EMB, &Al[(wrow + j * 8) * 64]);
            GLDS16(gb + (size_t)j * 8 * EMB, &Bl[(wrow + j * 8) * 64]);
        }
        __syncthreads();     // drains vmcnt -> staged tile visible

#pragma unroll
        for (int kk = 0; kk < 2; ++kk) {
            const int sl = kk ? sl1 : sl0;
            u16x8 a[4], b[4];
#pragma unroll
            for (int i = 0; i < 4; ++i)
                a[i] = *(const u16x8*)&Al[(wm * 64 + i * 16 + l15) * 64 + sl];
#pragma unroll
            for (int j = 0; j < 4; ++j)
                b[j] = *(const u16x8*)&Bl[(wn * 64 + j * 16 + l15) * 64 + sl];
#pragma unroll
            for (int i = 0; i < 4; ++i)
#pragma unroll
                for (int j = 0; j < 4; ++j)
                    acc[i][j] = mfma16(a[i], b[j], acc[i][j]);
        }
        __syncthreads();
    }

#pragma unroll
    for (int j = 0; j < 4; ++j) {
        int n = n0 + wn * 64 + j * 16 + l15;
        float bvv = bias[n];
        int h = n >> 6, d = n & 63;
#pragma unroll
        for (int i = 0; i < 4; ++i) {
#pragma unroll
            for (int r = 0; r < 4; ++r) {
                int m = m0 + wm * 64 + i * 16 + ((lane >> 4) << 2) + r;
                int bb = m >> 11, s = m & 2047;
                dst[((size_t)((bb * NH + h) * S_LEN + s)) * DK + d] =
                    f2bf(acc[i][j][r] + bvv);
            }
        }
    }
}

// ---------------------------------------------------------------- attention
// 8 waves: 4 q-waves (32 rows each, QT=128) x 2 K-parity groups (even/odd
// K-tiles, group-private LDS, LSE merge at end).  Swapped QK^T (32x32 MFMA),
// in-register exp2-domain softmax with defer-max, cvt_pk+permlane32 P->B.
__global__ __launch_bounds__(512) void attn_kernel(
    const unsigned short* __restrict__ Q,
    const unsigned short* __restrict__ K,
    const unsigned short* __restrict__ V,
    const int* __restrict__ mskp,
    float* __restrict__ out)
{
    const int tid = threadIdx.x, lane = tid & 63, wid = tid >> 6;
    const int grp = wid >> 2, qw = wid & 3;
    const int l31 = lane & 31, H = lane >> 5;
    const int bh = blockIdx.x;
    const int h  = bh & 15, b = bh >> 4;
    const int y  = blockIdx.y;
    const int qt = (y < 8) ? y : 23 - y;   // pairs (y,y+8): qt sums to 15
    const int q0 = qt * 128;
    const size_t hoff = ((size_t)(b * NH + h)) * S_LEN * DK;
    const unsigned short* Qh = Q + hoff;
    const unsigned short* Kh = K + hoff;
    const unsigned short* Vh = V + hoff;
    const int msk = *mskp;
    const int ntiles = msk ? (2 * qt + 2) : (S_LEN / KT);  // always even
    const int niter  = ntiles >> 1;

    __shared__ __align__(16) unsigned short Kl[2][64 * 64];
    __shared__ __align__(16) unsigned short Vt[2][64 * 64];
    __shared__ float MLbuf[512];           // merge m/l pairs (separate!)
    unsigned short* Kg = Kl[grp];
    unsigned short* Vg = Vt[grp];

    const int qrow = q0 + qw * 32 + l31;
    u16x8 qf[4];
#pragma unroll
    for (int ks = 0; ks < 4; ++ks)
        qf[ks] = *(const u16x8*)(Qh + (size_t)qrow * DK + ks * 16 + H * 8);

    f32x16 o0, o1;
#pragma unroll
    for (int i = 0; i < 16; ++i) { o0[i] = 0.f; o1[i] = 0.f; }
    float mx = -1e30f, lsum = 0.f;

    const int gt  = tid & 255;              // thread within group
    const int sr0 = gt >> 3, sc8 = gt & 7, sr1 = sr0 + 32;
    const int kwo0 = sr0 * 64 + ((sc8 ^ (sr0 & 7)) << 3);
    const int kwo1 = sr1 * 64 + ((sc8 ^ (sr1 & 7)) << 3);
    const int vwo0 = (((sr0 >> 3) ^ sc8) << 3) + (sr0 & 7);
    const int vwo1 = (((sr1 >> 3) ^ sc8) << 3) + (sr1 & 7);

    u16x8 kr[2], vr[2];
    {
        const unsigned short* K0 = Kh + (size_t)grp * KT * DK;
        const unsigned short* V0 = Vh + (size_t)grp * KT * DK;
        kr[0] = *(const u16x8*)(K0 + (size_t)sr0 * DK + sc8 * 8);
        vr[0] = *(const u16x8*)(V0 + (size_t)sr0 * DK + sc8 * 8);
        kr[1] = *(const u16x8*)(K0 + (size_t)sr1 * DK + sc8 * 8);
        vr[1] = *(const u16x8*)(V0 + (size_t)sr1 * DK + sc8 * 8);
    }

    const int qmin = q0 + qw * 32;
    const int dsw0 = l31 >> 3, dsw1 = 4 + (l31 >> 3);
    const int rsw  = l31 & 7;
    const float SC2 = 0.125f * 1.4426950408889634f;   // fold log2(e)

    for (int it = 0; it < niter; ++it) {
        const int kt = 2 * it + grp;
        __syncthreads();   // group's readers done with its LDS tile
        *(u16x8*)&Kg[kwo0] = kr[0];
        *(u16x8*)&Kg[kwo1] = kr[1];
#pragma unroll
        for (int e = 0; e < 8; ++e) {
            Vg[(sc8 * 8 + e) * 64 + vwo0] = vr[0][e];
            Vg[(sc8 * 8 + e) * 64 + vwo1] = vr[1][e];
        }
        __syncthreads();

        if (it + 1 < niter) {   // prefetch this group's next tile
            const unsigned short* Kn = Kh + (size_t)(kt + 2) * KT * DK;
            const unsigned short* Vn = Vh + (size_t)(kt + 2) * KT * DK;
            kr[0] = *(const u16x8*)(Kn + (size_t)sr0 * DK + sc8 * 8);
            vr[0] = *(const u16x8*)(Vn + (size_t)sr0 * DK + sc8 * 8);
            kr[1] = *(const u16x8*)(Kn + (size_t)sr1 * DK + sc8 * 8);
            vr[1] = *(const u16x8*)(Vn + (size_t)sr1 * DK + sc8 * 8);
        }

        if (msk && kt * KT > qmin + 31) continue;  // wave-uniform skip

        // ---- S^T = K Q^T ----
        f32x16 st0, st1;
#pragma unroll
        for (int i = 0; i < 16; ++i) { st0[i] = 0.f; st1[i] = 0.f; }
        __builtin_amdgcn_s_setprio(1);
#pragma unroll
        for (int ks = 0; ks < 4; ++ks) {
            const int g = (((ks << 1) + H) ^ rsw) << 3;
            u16x8 kf0 = *(const u16x8*)&Kg[l31 * 64 + g];
            u16x8 kf1 = *(const u16x8*)&Kg[(32 + l31) * 64 + g];
            st0 = mfma32(kf0, qf[ks], st0);
            st1 = mfma32(kf1, qf[ks], st1);
        }
        __builtin_amdgcn_s_setprio(0);

        // ---- scale (exp2 domain) + causal mask ----
        const bool needmask = msk && (kt * KT + 63 > qrow);
        float p[32];
#pragma unroll
        for (int r = 0; r < 16; ++r) {
            const int krow = (r & 3) + 8 * (r >> 2) + 4 * H;
            float v0 = st0[r] * SC2;
            float v1 = st1[r] * SC2;
            if (needmask) {
                if (kt * KT + krow > qrow)      v0 = -1e30f;
                if (kt * KT + 32 + krow > qrow) v1 = -1e30f;
            }
            p[r] = v0; p[16 + r] = v1;
        }

        // ---- online softmax: register tree + one shfl(32); defer-max ----
        float t8[8];
#pragma unroll
        for (int i = 0; i < 8; ++i)
            t8[i] = fmaxf(fmaxf(p[i], p[i + 8]), fmaxf(p[i + 16], p[i + 24]));
#pragma unroll
        for (int i = 0; i < 4; ++i) t8[i] = fmaxf(t8[i], t8[i + 4]);
        float mt = fmaxf(fmaxf(t8[0], t8[1]), fmaxf(t8[2], t8[3]));
        mt = fmaxf(mt, __shfl_xor(mt, 32, 64));

        if (!__all(mt <= mx + 11.54f)) {   // 8 nats in log2 domain
            const float mn = fmaxf(mx, mt);
            const float al = exp2_hw(mx - mn);
            mx = mn;
            lsum *= al;
#pragma unroll
            for (int i = 0; i < 16; ++i) { o0[i] *= al; o1[i] *= al; }
        }

        float s8[8];
#pragma unroll
        for (int i = 0; i < 8; ++i) s8[i] = 0.f;
#pragma unroll
        for (int r = 0; r < 32; ++r) {
            p[r] = exp2_hw(p[r] - mx);
            s8[r & 7] += p[r];
        }
        float ls = ((s8[0] + s8[1]) + (s8[2] + s8[3])) +
                   ((s8[4] + s8[5]) + (s8[6] + s8[7]));
        ls += __shfl_xor(ls, 32, 64);
        lsum += ls;

        // ---- P^T -> bf16 B-fragments, then PV ----
        __builtin_amdgcn_s_setprio(1);
#pragma unroll
        for (int ks = 0; ks < 4; ++ks) {
            const int bb = ks * 8;
            unsigned int wa, wb2, wc, wd;
            asm("v_cvt_pk_bf16_f32 %0, %1, %2" : "=v"(wa)  : "v"(p[bb + 0]), "v"(p[bb + 1]));
            asm("v_cvt_pk_bf16_f32 %0, %1, %2" : "=v"(wb2) : "v"(p[bb + 2]), "v"(p[bb + 3]));
            asm("v_cvt_pk_bf16_f32 %0, %1, %2" : "=v"(wc)  : "v"(p[bb + 4]), "v"(p[bb + 5]));
            asm("v_cvt_pk_bf16_f32 %0, %1, %2" : "=v"(wd)  : "v"(p[bb + 6]), "v"(p[bb + 7]));
            asm volatile("v_permlane32_swap_b32 %0, %1" : "+v"(wa),  "+v"(wc));
            asm volatile("v_permlane32_swap_b32 %0, %1" : "+v"(wb2), "+v"(wd));
            u32x4 wv; wv[0] = wa; wv[1] = wb2; wv[2] = wc; wv[3] = wd;
            const u16x8 pb = __builtin_bit_cast(u16x8, wv);
            const int kg = (ks << 1) + H;
            u16x8 vf0 = *(const u16x8*)&Vg[l31 * 64        + ((kg ^ dsw0) << 3)];
            u16x8 vf1 = *(const u16x8*)&Vg[(32 + l31) * 64 + ((kg ^ dsw1) << 3)];
            o0 = mfma32(vf0, pb, o0);
            o1 = mfma32(vf1, pb, o1);
        }
        __builtin_amdgcn_s_setprio(0);
    }

    // ---- merge group 0 + group 1 (LSE combine) ----
    // MO: 256 rows x 32 floats = 32 KB, split exactly across Kl (idx<128)
    // and Vt (idx>=128); m/l pairs live in the separate MLbuf.
    const int idx = qw * 64 + lane;
    float* MO = (idx < 128) ? ((float*)Kl + idx * 32)
                            : ((float*)Vt + (idx - 128) * 32);
    __syncthreads();
    if (grp == 1) {
#pragma unroll
        for (int i = 0; i < 16; ++i) {
            MO[(i + idx) & 31]      = o0[i];
            MO[(16 + i + idx) & 31] = o1[i];
        }
        MLbuf[idx * 2]     = mx;
        MLbuf[idx * 2 + 1] = lsum;
    }
    __syncthreads();
    if (grp == 0) {
        const float m2 = MLbuf[idx * 2], l2 = MLbuf[idx * 2 + 1];
        const float mn = fmaxf(mx, m2);
        const float ea = exp2_hw(mx - mn);
        const float eb = exp2_hw(m2 - mn);
        const float inv = 1.f / (lsum * ea + l2 * eb);
        float* orow = out + ((size_t)(b * S_LEN) + qrow) * EMB + h * DK;
#pragma unroll
        for (int g = 0; g < 4; ++g) {
            f32x4 w0, w1;
#pragma unroll
            for (int i = 0; i < 4; ++i) {
                w0[i] = (o0[4 * g + i] * ea + MO[(4 * g + i + idx) & 31] * eb) * inv;
                w1[i] = (o1[4 * g + i] * ea + MO[(16 + 4 * g + i + idx) & 31] * eb) * inv;
            }
            *(f32x4*)&orow[8 * g + 4 * H]      = w0;
            *(f32x4*)&orow[32 + 8 * g + 4 * H] = w1;
        }
    }
}

// ---------------------------------------------------------------- launch
extern "C" void kernel_launch(void* const* d_in, const int* in_sizes, int n_in,
                              void* d_out, int out_size, void* d_ws, size_t ws_size,
                              hipStream_t stream)
{
    const float* x  = (const float*)d_in[0];
    const float* wq = (const float*)d_in[1];
    const float* bq = (const float*)d_in[2];
    const float* wk = (const float*)d_in[3];
    const float* bk = (const float*)d_in[4];
    const float* wv = (const float*)d_in[5];
    const float* bv = (const float*)d_in[6];
    const int* msk  = (const int*)d_in[7];
    float* out = (float*)d_out;

    unsigned short* xb  = (unsigned short*)d_ws;
    unsigned short* wb  = xb + (size_t)M_TOT * EMB;
    unsigned short* qkv = wb + (size_t)3 * 1024 * 1024;

    cvt_kernel<<<7168, 256, 0, stream>>>(x, wq, wk, wv,
                                         xb, wb, wb + 1024 * 1024, wb + 2 * 1024 * 1024);
    qkv_gemm<<<dim3(8, 32, 3), 256, 0, stream>>>(xb, wb, bq, bk, bv, qkv);
    attn_kernel<<<dim3(32, 16, 1), 512, 0, stream>>>(
        qkv, qkv + (size_t)M_TOT * EMB, qkv + (size_t)2 * M_TOT * EMB, msk, out);
}

// Round 8
// 91.765 us; speedup vs baseline: 2.4306x; 1.0459x over previous
//
#include <hip/hip_runtime.h>

#define B_SZ   2
#define NH     16
#define S_LEN  2048
#define DK     64
#define EMB    1024
#define M_TOT  (B_SZ * S_LEN)   // 4096
#define KT     64

typedef float          f32x4  __attribute__((ext_vector_type(4)));
typedef float          f32x16 __attribute__((ext_vector_type(16)));
typedef unsigned int   u32x4  __attribute__((ext_vector_type(4)));
typedef unsigned short u16x8  __attribute__((ext_vector_type(8)));
typedef unsigned short u16x4  __attribute__((ext_vector_type(4)));
typedef __bf16         bf16x8 __attribute__((ext_vector_type(8)));

static __device__ __forceinline__ f32x4 mfma16(u16x8 a, u16x8 b, f32x4 c) {
    return __builtin_amdgcn_mfma_f32_16x16x32_bf16(
        __builtin_bit_cast(bf16x8, a), __builtin_bit_cast(bf16x8, b), c, 0, 0, 0);
}
static __device__ __forceinline__ f32x16 mfma32(u16x8 a, u16x8 b, f32x16 c) {
    return __builtin_amdgcn_mfma_f32_32x32x16_bf16(
        __builtin_bit_cast(bf16x8, a), __builtin_bit_cast(bf16x8, b), c, 0, 0, 0);
}

// round-to-nearest-even fp32 -> bf16 (finite inputs)
static __device__ __forceinline__ unsigned short f2bf(float f) {
    unsigned int u = __builtin_bit_cast(unsigned int, f);
    u = (u + 0x7FFFu + ((u >> 16) & 1u)) >> 16;
    return (unsigned short)u;
}

// hardware 2^x
static __device__ __forceinline__ float exp2_hw(float x) {
    float r; asm("v_exp_f32 %0, %1" : "=v"(r) : "v"(x)); return r;
}

// async global -> LDS, 16B per lane; LDS dest = uniform base + lane*16
#define GLDS16(g, l)  __builtin_amdgcn_global_load_lds(                      \
    (const void __attribute__((address_space(1)))*)(g),                      \
    (void __attribute__((address_space(3)))*)(l), 16, 0, 0)

// ---------------------------------------------------------------- convert
__global__ __launch_bounds__(256) void cvt_kernel(
    const float* __restrict__ x,  const float* __restrict__ wq,
    const float* __restrict__ wk, const float* __restrict__ wv,
    unsigned short* __restrict__ xb,  unsigned short* __restrict__ wqb,
    unsigned short* __restrict__ wkb, unsigned short* __restrict__ wvb)
{
    long gid = (long)blockIdx.x * 256 + threadIdx.x;
    long e = gid * 4;
    const float* src; unsigned short* dst; long off;
    if      (e < 4194304L) { src = x;  dst = xb;  off = e; }
    else if (e < 5242880L) { src = wq; dst = wqb; off = e - 4194304L; }
    else if (e < 6291456L) { src = wk; dst = wkb; off = e - 5242880L; }
    else                   { src = wv; dst = wvb; off = e - 6291456L; }
    f32x4 v = *(const f32x4*)(src + off);
    u16x4 u;
    u[0] = f2bf(v[0]); u[1] = f2bf(v[1]); u[2] = f2bf(v[2]); u[3] = f2bf(v[3]);
    *(u16x4*)(dst + off) = u;
}

// ---------------------------------------------------------------- QKV GEMM
// m97 template + both-sides XOR swizzle (rule #21):
//   LDS linear [row][64]; global SOURCE pre-swizzled so LDS(row, slot) holds
//   global slot (slot ^ (row&7)); fragment read XORs slot with (l15&7).
#define BM 128
#define BN 128
#define BK 64

__global__ __launch_bounds__(256) void qkv_gemm(
    const unsigned short* __restrict__ xb,
    const unsigned short* __restrict__ wb,
    const float* __restrict__ bq, const float* __restrict__ bk,
    const float* __restrict__ bv,
    unsigned short* __restrict__ qkv)
{
    const int tid  = threadIdx.x;
    const int lane = tid & 63;
    const int wid  = tid >> 6;
    const int wm   = wid >> 1, wn = wid & 1;
    const int n0   = blockIdx.x * BN;
    const int m0   = blockIdx.y * BM;
    const int mat  = blockIdx.z;

    const unsigned short* wmat = wb + (size_t)mat * (1024 * 1024);
    const float* bias = (mat == 0) ? bq : ((mat == 1) ? bk : bv);
    unsigned short* dst = qkv + (size_t)mat * ((size_t)M_TOT * EMB);

    __shared__ __align__(16) unsigned short Al[BM * 64];
    __shared__ __align__(16) unsigned short Bl[BN * 64];

    f32x4 acc[4][4];
#pragma unroll
    for (int i = 0; i < 4; ++i)
#pragma unroll
        for (int j = 0; j < 4; ++j)
            acc[i][j] = (f32x4){0.f, 0.f, 0.f, 0.f};

    const int wrow = wid * 32;                    // wave's staging row block
    const int lrow = lane >> 3;                   // row within 8-row stripe
    const int lcol = ((lane & 7) ^ lrow) * 8;     // PRE-SWIZZLED source slot
    const int l15  = lane & 15;
    // fragment-read slots (slot = (kk*4 + lane>>4) ^ (row&7), row&7 = l15&7)
    const int sl0 = (((lane >> 4))     ^ (l15 & 7)) * 8;   // kk = 0
    const int sl1 = ((4 + (lane >> 4)) ^ (l15 & 7)) * 8;   // kk = 1

    for (int k0 = 0; k0 < EMB; k0 += BK) {
        const unsigned short* ga = xb   + (size_t)(m0 + wrow + lrow) * EMB + k0 + lcol;
        const unsigned short* gb = wmat + (size_t)(n0 + wrow + lrow) * EMB + k0 + lcol;
#pragma unroll
        for (int j = 0; j < 4; ++j) {
            GLDS16(ga + (size_t)j * 8 * EMB, &Al[(wrow + j * 8) * 64]);
            GLDS16(gb + (size_t)j * 8 * EMB, &Bl[(wrow + j * 8) * 64]);
        }
        __syncthreads();     // drains vmcnt -> staged tile visible

#pragma unroll
        for (int kk = 0; kk < 2; ++kk) {
            const int sl = kk ? sl1 : sl0;
            u16x8 a[4], b[4];
#pragma unroll
            for (int i = 0; i < 4; ++i)
                a[i] = *(const u16x8*)&Al[(wm * 64 + i * 16 + l15) * 64 + sl];
#pragma unroll
            for (int j = 0; j < 4; ++j)
                b[j] = *(const u16x8*)&Bl[(wn * 64 + j * 16 + l15) * 64 + sl];
#pragma unroll
            for (int i = 0; i < 4; ++i)
#pragma unroll
                for (int j = 0; j < 4; ++j)
                    acc[i][j] = mfma16(a[i], b[j], acc[i][j]);
        }
        __syncthreads();
    }

#pragma unroll
    for (int j = 0; j < 4; ++j) {
        int n = n0 + wn * 64 + j * 16 + l15;
        float bvv = bias[n];
        int h = n >> 6, d = n & 63;
#pragma unroll
        for (int i = 0; i < 4; ++i) {
#pragma unroll
            for (int r = 0; r < 4; ++r) {
                int m = m0 + wm * 64 + i * 16 + ((lane >> 4) << 2) + r;
                int bb = m >> 11, s = m & 2047;
                dst[((size_t)((bb * NH + h) * S_LEN + s)) * DK + d] =
                    f2bf(acc[i][j][r] + bvv);
            }
        }
    }
}

// ---------------------------------------------------------------- attention
// 8 waves = 4 q-waves x 2 K-parity groups.  Single-barrier double-buffered
// pipeline: per iter {write tile t+1 -> buf^1, prefetch t+2, compute buf}.
// Swapped QK^T (32x32 MFMA), in-register exp2 softmax with defer-max,
// row-sum via mfma32(ones, P) into lacc (no VALU adds), cvt_pk+permlane P->B.
__global__ __launch_bounds__(512) void attn_kernel(
    const unsigned short* __restrict__ Q,
    const unsigned short* __restrict__ K,
    const unsigned short* __restrict__ V,
    const int* __restrict__ mskp,
    float* __restrict__ out)
{
    const int tid = threadIdx.x, lane = tid & 63, wid = tid >> 6;
    const int grp = wid >> 2, qw = wid & 3;
    const int l31 = lane & 31, H = lane >> 5;
    const int bh = blockIdx.x;
    const int h  = bh & 15, b = bh >> 4;
    const int y  = blockIdx.y;
    const int qt = (y < 8) ? y : 23 - y;   // pairs (y,y+8): qt sums to 15
    const int q0 = qt * 128;
    const size_t hoff = ((size_t)(b * NH + h)) * S_LEN * DK;
    const unsigned short* Qh = Q + hoff;
    const unsigned short* Kh = K + hoff;
    const unsigned short* Vh = V + hoff;
    const int msk = *mskp;
    const int ntiles = msk ? (2 * qt + 2) : (S_LEN / KT);  // always even
    const int niter  = ntiles >> 1;

    __shared__ __align__(16) unsigned short Kl[2][2][64 * 64];  // [grp][buf]
    __shared__ __align__(16) unsigned short Vt[2][2][64 * 64];
    __shared__ float MLbuf[512];

    const int qrow = q0 + qw * 32 + l31;
    u16x8 qf[4];
#pragma unroll
    for (int ks = 0; ks < 4; ++ks)
        qf[ks] = *(const u16x8*)(Qh + (size_t)qrow * DK + ks * 16 + H * 8);

    u16x8 ones1;
#pragma unroll
    for (int i = 0; i < 8; ++i) ones1[i] = 0x3F80;   // bf16 1.0

    f32x16 o0, o1, lacc;
#pragma unroll
    for (int i = 0; i < 16; ++i) { o0[i] = 0.f; o1[i] = 0.f; lacc[i] = 0.f; }
    float mx = -1e30f;

    const int gt  = tid & 255;              // thread within group
    const int sr0 = gt >> 3, sc8 = gt & 7, sr1 = sr0 + 32;
    const int kwo0 = sr0 * 64 + ((sc8 ^ (sr0 & 7)) << 3);
    const int kwo1 = sr1 * 64 + ((sc8 ^ (sr1 & 7)) << 3);
    const int vwo0 = (((sr0 >> 3) ^ sc8) << 3) + (sr0 & 7);
    const int vwo1 = (((sr1 >> 3) ^ sc8) << 3) + (sr1 & 7);

    const int qmin = q0 + qw * 32;
    const int dsw0 = l31 >> 3, dsw1 = 4 + (l31 >> 3);
    const int rsw  = l31 & 7;
    const float SC2 = 0.125f * 1.4426950408889634f;   // fold log2(e)

    // ---- prologue: stage tile 'grp' into buf0, prefetch tile grp+2 ----
    u16x8 kr[2], vr[2];
    {
        const unsigned short* K0 = Kh + (size_t)grp * KT * DK;
        const unsigned short* V0 = Vh + (size_t)grp * KT * DK;
        kr[0] = *(const u16x8*)(K0 + (size_t)sr0 * DK + sc8 * 8);
        vr[0] = *(const u16x8*)(V0 + (size_t)sr0 * DK + sc8 * 8);
        kr[1] = *(const u16x8*)(K0 + (size_t)sr1 * DK + sc8 * 8);
        vr[1] = *(const u16x8*)(V0 + (size_t)sr1 * DK + sc8 * 8);
        unsigned short* Kg = Kl[grp][0];
        unsigned short* Vg = Vt[grp][0];
        *(u16x8*)&Kg[kwo0] = kr[0];
        *(u16x8*)&Kg[kwo1] = kr[1];
#pragma unroll
        for (int e = 0; e < 8; ++e) {
            Vg[(sc8 * 8 + e) * 64 + vwo0] = vr[0][e];
            Vg[(sc8 * 8 + e) * 64 + vwo1] = vr[1][e];
        }
        if (grp + 2 < ntiles) {
            const unsigned short* Kn = Kh + (size_t)(grp + 2) * KT * DK;
            const unsigned short* Vn = Vh + (size_t)(grp + 2) * KT * DK;
            kr[0] = *(const u16x8*)(Kn + (size_t)sr0 * DK + sc8 * 8);
            vr[0] = *(const u16x8*)(Vn + (size_t)sr0 * DK + sc8 * 8);
            kr[1] = *(const u16x8*)(Kn + (size_t)sr1 * DK + sc8 * 8);
            vr[1] = *(const u16x8*)(Vn + (size_t)sr1 * DK + sc8 * 8);
        }
    }
    __syncthreads();

    int cur = 0;
    for (int it = 0; it < niter; ++it) {
        const int kt = 2 * it + grp;   // kt <= ntiles-1 always

        // ---- write NEXT tile (kt+2) into buf^1; overlaps with compute ----
        if (kt + 2 < ntiles) {
            unsigned short* Kg = Kl[grp][cur ^ 1];
            unsigned short* Vg = Vt[grp][cur ^ 1];
            *(u16x8*)&Kg[kwo0] = kr[0];
            *(u16x8*)&Kg[kwo1] = kr[1];
#pragma unroll
            for (int e = 0; e < 8; ++e) {
                Vg[(sc8 * 8 + e) * 64 + vwo0] = vr[0][e];
                Vg[(sc8 * 8 + e) * 64 + vwo1] = vr[1][e];
            }
        }
        // ---- prefetch tile kt+4 into regs ----
        if (kt + 4 < ntiles) {
            const unsigned short* Kn = Kh + (size_t)(kt + 4) * KT * DK;
            const unsigned short* Vn = Vh + (size_t)(kt + 4) * KT * DK;
            kr[0] = *(const u16x8*)(Kn + (size_t)sr0 * DK + sc8 * 8);
            vr[0] = *(const u16x8*)(Vn + (size_t)sr0 * DK + sc8 * 8);
            kr[1] = *(const u16x8*)(Kn + (size_t)sr1 * DK + sc8 * 8);
            vr[1] = *(const u16x8*)(Vn + (size_t)sr1 * DK + sc8 * 8);
        }

        // ---- compute tile kt from buf[cur] (skip if fully masked) ----
        if (!(msk && kt * KT > qmin + 31)) {
            const unsigned short* Kg = Kl[grp][cur];
            const unsigned short* Vg = Vt[grp][cur];

            // S^T = K Q^T
            f32x16 st0, st1;
#pragma unroll
            for (int i = 0; i < 16; ++i) { st0[i] = 0.f; st1[i] = 0.f; }
            __builtin_amdgcn_s_setprio(1);
#pragma unroll
            for (int ks = 0; ks < 4; ++ks) {
                const int g = (((ks << 1) + H) ^ rsw) << 3;
                u16x8 kf0 = *(const u16x8*)&Kg[l31 * 64 + g];
                u16x8 kf1 = *(const u16x8*)&Kg[(32 + l31) * 64 + g];
                st0 = mfma32(kf0, qf[ks], st0);
                st1 = mfma32(kf1, qf[ks], st1);
            }
            __builtin_amdgcn_s_setprio(0);

            // scale (exp2 domain, packed) + causal mask
            st0 *= SC2;
            st1 *= SC2;
            float p[32];
#pragma unroll
            for (int r = 0; r < 16; ++r) { p[r] = st0[r]; p[16 + r] = st1[r]; }
            const bool needmask = msk && (kt * KT + 63 > qrow);
            if (needmask) {
#pragma unroll
                for (int r = 0; r < 16; ++r) {
                    const int krow = (r & 3) + 8 * (r >> 2) + 4 * H;
                    if (kt * KT + krow > qrow)      p[r]      = -1e30f;
                    if (kt * KT + 32 + krow > qrow) p[16 + r] = -1e30f;
                }
            }

            // tile max: register tree + one shfl(32); defer-max rescale
            float t8[8];
#pragma unroll
            for (int i = 0; i < 8; ++i)
                t8[i] = fmaxf(fmaxf(p[i], p[i + 8]), fmaxf(p[i + 16], p[i + 24]));
#pragma unroll
            for (int i = 0; i < 4; ++i) t8[i] = fmaxf(t8[i], t8[i + 4]);
            float mt = fmaxf(fmaxf(t8[0], t8[1]), fmaxf(t8[2], t8[3]));
            mt = fmaxf(mt, __shfl_xor(mt, 32, 64));

            if (!__all(mt <= mx + 11.54f)) {   // 8 nats in log2 domain
                const float mn = fmaxf(mx, mt);
                const float al = exp2_hw(mx - mn);
                mx = mn;
                o0 *= al; o1 *= al;
                lacc[0] *= al;                  // only reg 0 of lacc is used
            }

#pragma unroll
            for (int r = 0; r < 32; ++r) p[r] = exp2_hw(p[r] - mx);

            // P^T -> bf16 B-fragments; PV + row-sum via ones-MFMA
            __builtin_amdgcn_s_setprio(1);
#pragma unroll
            for (int ks = 0; ks < 4; ++ks) {
                const int bb = ks * 8;
                unsigned int wa, wb2, wc, wd;
                asm("v_cvt_pk_bf16_f32 %0, %1, %2" : "=v"(wa)  : "v"(p[bb + 0]), "v"(p[bb + 1]));
                asm("v_cvt_pk_bf16_f32 %0, %1, %2" : "=v"(wb2) : "v"(p[bb + 2]), "v"(p[bb + 3]));
                asm("v_cvt_pk_bf16_f32 %0, %1, %2" : "=v"(wc)  : "v"(p[bb + 4]), "v"(p[bb + 5]));
                asm("v_cvt_pk_bf16_f32 %0, %1, %2" : "=v"(wd)  : "v"(p[bb + 6]), "v"(p[bb + 7]));
                asm volatile("v_permlane32_swap_b32 %0, %1" : "+v"(wa),  "+v"(wc));
                asm volatile("v_permlane32_swap_b32 %0, %1" : "+v"(wb2), "+v"(wd));
                u32x4 wv; wv[0] = wa; wv[1] = wb2; wv[2] = wc; wv[3] = wd;
                const u16x8 pb = __builtin_bit_cast(u16x8, wv);
                const int kg = (ks << 1) + H;
                u16x8 vf0 = *(const u16x8*)&Vg[l31 * 64        + ((kg ^ dsw0) << 3)];
                u16x8 vf1 = *(const u16x8*)&Vg[(32 + l31) * 64 + ((kg ^ dsw1) << 3)];
                o0 = mfma32(vf0, pb, o0);
                o1 = mfma32(vf1, pb, o1);
                lacc = mfma32(ones1, pb, lacc);
            }
            __builtin_amdgcn_s_setprio(0);
        }

        __syncthreads();   // writes of buf^1 visible; readers of buf done
        cur ^= 1;
    }

    // ---- merge group 0 + group 1 (LSE combine) ----
    // MO: 256 rows x 32 floats = 32 KB = exactly sizeof(Kl).
    const int idx = qw * 64 + lane;
    float* MO = (float*)Kl + idx * 32;
    const float lsum = lacc[0];
    if (grp == 1) {
#pragma unroll
        for (int i = 0; i < 16; ++i) {
            MO[(i + idx) & 31]      = o0[i];
            MO[(16 + i + idx) & 31] = o1[i];
        }
        MLbuf[idx * 2]     = mx;
        MLbuf[idx * 2 + 1] = lsum;
    }
    __syncthreads();
    if (grp == 0) {
        const float m2 = MLbuf[idx * 2], l2 = MLbuf[idx * 2 + 1];
        const float mn = fmaxf(mx, m2);
        const float ea = exp2_hw(mx - mn);
        const float eb = exp2_hw(m2 - mn);
        const float inv = 1.f / (lsum * ea + l2 * eb);
        float* orow = out + ((size_t)(b * S_LEN) + qrow) * EMB + h * DK;
#pragma unroll
        for (int g = 0; g < 4; ++g) {
            f32x4 w0, w1;
#pragma unroll
            for (int i = 0; i < 4; ++i) {
                w0[i] = (o0[4 * g + i] * ea + MO[(4 * g + i + idx) & 31] * eb) * inv;
                w1[i] = (o1[4 * g + i] * ea + MO[(16 + 4 * g + i + idx) & 31] * eb) * inv;
            }
            *(f32x4*)&orow[8 * g + 4 * H]      = w0;
            *(f32x4*)&orow[32 + 8 * g + 4 * H] = w1;
        }
    }
}

// ---------------------------------------------------------------- launch
extern "C" void kernel_launch(void* const* d_in, const int* in_sizes, int n_in,
                              void* d_out, int out_size, void* d_ws, size_t ws_size,
                              hipStream_t stream)
{
    const float* x  = (const float*)d_in[0];
    const float* wq = (const float*)d_in[1];
    const float* bq = (const float*)d_in[2];
    const float* wk = (const float*)d_in[3];
    const float* bk = (const float*)d_in[4];
    const float* wv = (const float*)d_in[5];
    const float* bv = (const float*)d_in[6];
    const int* msk  = (const int*)d_in[7];
    float* out = (float*)d_out;

    unsigned short* xb  = (unsigned short*)d_ws;
    unsigned short* wb  = xb + (size_t)M_TOT * EMB;
    unsigned short* qkv = wb + (size_t)3 * 1024 * 1024;

    cvt_kernel<<<7168, 256, 0, stream>>>(x, wq, wk, wv,
                                         xb, wb, wb + 1024 * 1024, wb + 2 * 1024 * 1024);
    qkv_gemm<<<dim3(8, 32, 3), 256, 0, stream>>>(xb, wb, bq, bk, bv, qkv);
    attn_kernel<<<dim3(32, 16, 1), 512, 0, stream>>>(
        qkv, qkv + (size_t)M_TOT * EMB, qkv + (size_t)2 * M_TOT * EMB, msk, out);
}